// Round 1
// baseline (973.580 us; speedup 1.0000x reference)
//
#include <hip/hip_runtime.h>

#define HID 64
#define NF 5
#define NC 5

// ---------------- CSR build ----------------

__global__ void k_zero_i32(int* __restrict__ p, int n) {
    int i = blockIdx.x * blockDim.x + threadIdx.x;
    if (i < n) p[i] = 0;
}

__global__ void k_hist(const int* __restrict__ dst, int E, int* __restrict__ deg) {
    int i = blockIdx.x * blockDim.x + threadIdx.x;
    if (i < E) atomicAdd(deg + dst[i], 1);
}

// Single-block exclusive scan over deg[N] -> offsets[N+1], cursor[N]; also dinv = rsqrt(deg+1).
__global__ __launch_bounds__(1024) void k_scan(const int* __restrict__ deg, int N,
                                               int* __restrict__ offsets,
                                               int* __restrict__ cursor,
                                               float* __restrict__ dinv) {
    __shared__ int sums[1024];
    int t = threadIdx.x;
    int T = (N + 1023) >> 10;              // items per thread
    int begin = t * T;
    int end = begin + T; if (end > N) end = N;
    int local = 0;
    for (int i = begin; i < end; ++i) local += deg[i];
    sums[t] = local;
    __syncthreads();
    // Hillis-Steele inclusive scan over 1024 thread sums
    for (int off = 1; off < 1024; off <<= 1) {
        int v = (t >= off) ? sums[t - off] : 0;
        __syncthreads();
        sums[t] += v;
        __syncthreads();
    }
    int run = sums[t] - local;             // exclusive base for this thread's range
    for (int i = begin; i < end; ++i) {
        int d = deg[i];
        offsets[i] = run;
        cursor[i] = run;
        dinv[i] = rsqrtf((float)d + 1.0f);
        run += d;
    }
    if (t == 0) offsets[N] = sums[1023];
}

__global__ void k_scatter(const int* __restrict__ src, const int* __restrict__ dst, int E,
                          int* __restrict__ cursor, int* __restrict__ csr_src) {
    int i = blockIdx.x * blockDim.x + threadIdx.x;
    if (i < E) {
        int d = dst[i];
        int pos = atomicAdd(cursor + d, 1);
        csr_src[pos] = src[i];
    }
}

// ---------------- GCN layers ----------------

// linS[n][f] = (sum_k x[n,3,k] * W1[k][f]) * dinv[n]
__global__ void k_lin1(const float* __restrict__ x, const float* __restrict__ W1,
                       const float* __restrict__ dinv, float* __restrict__ linS, int N) {
    int gid = blockIdx.x * blockDim.x + threadIdx.x;
    int n = gid >> 6, f = gid & 63;
    if (n >= N) return;
    const float* xr = x + (size_t)n * (4 * NF) + 3 * NF;   // x[n, 3, :]
    float acc = 0.f;
#pragma unroll
    for (int k = 0; k < NF; ++k) acc += xr[k] * W1[k * HID + f];
    linS[(size_t)n * HID + f] = acc * dinv[n];
}

// linS2[n][f] = (sum_k h[n,k] * W2[k][f]) * dinv[n]   (W2 staged in LDS)
__global__ void k_lin2(const float* __restrict__ h, const float* __restrict__ W2,
                       const float* __restrict__ dinv, float* __restrict__ linS, int N) {
    __shared__ float sW[HID * HID];
    for (int i = threadIdx.x; i < HID * HID; i += blockDim.x) sW[i] = W2[i];
    __syncthreads();
    int gid = blockIdx.x * blockDim.x + threadIdx.x;
    int n = gid >> 6, f = gid & 63;
    if (n >= N) return;
    const float* hr = h + (size_t)n * HID;
    float acc = 0.f;
#pragma unroll 8
    for (int k = 0; k < HID; ++k) acc += hr[k] * sW[k * HID + f];
    linS[(size_t)n * HID + f] = acc * dinv[n];
}

// out[d][f] = relu( dinv[d] * (linS[d][f] + sum_{e in in(d)} linS[src_e][f]) + b[f] )
__global__ void k_agg(const float* __restrict__ linS, const int* __restrict__ offsets,
                      const int* __restrict__ csr_src, const float* __restrict__ dinv,
                      const float* __restrict__ bias, float* __restrict__ out, int N) {
    int wid = (blockIdx.x * blockDim.x + threadIdx.x) >> 6;
    int f = threadIdx.x & 63;
    if (wid >= N) return;
    float acc = linS[(size_t)wid * HID + f];
    int e0 = offsets[wid], e1 = offsets[wid + 1];
    for (int e = e0; e < e1; ++e) {
        int s = csr_src[e];
        acc += linS[(size_t)s * HID + f];
    }
    float v = dinv[wid] * acc + bias[f];
    out[(size_t)wid * HID + f] = fmaxf(v, 0.f);
}

// softmax(h @ Wout + bout): one wave per node, lane = hidden index
__global__ void k_out(const float* __restrict__ h, const float* __restrict__ Wout,
                      const float* __restrict__ bout, float* __restrict__ out, int N) {
    int wid = (blockIdx.x * blockDim.x + threadIdx.x) >> 6;
    int lane = threadIdx.x & 63;
    if (wid >= N) return;
    float hv = h[(size_t)wid * HID + lane];
    float logit[NC];
#pragma unroll
    for (int c = 0; c < NC; ++c) {
        float p = hv * Wout[lane * NC + c];
#pragma unroll
        for (int o = 32; o > 0; o >>= 1) p += __shfl_xor(p, o, 64);
        logit[c] = p + bout[c];
    }
    if (lane < NC) {
        float m = logit[0];
#pragma unroll
        for (int c = 1; c < NC; ++c) m = fmaxf(m, logit[c]);
        float s = 0.f;
        float ex[NC];
#pragma unroll
        for (int c = 0; c < NC; ++c) { ex[c] = __expf(logit[c] - m); s += ex[c]; }
        out[(size_t)wid * NC + lane] = ex[lane] / s;
    }
}

// ---------------- launch ----------------

extern "C" void kernel_launch(void* const* d_in, const int* in_sizes, int n_in,
                              void* d_out, int out_size, void* d_ws, size_t ws_size,
                              hipStream_t stream) {
    const float* x   = (const float*)d_in[0];
    const int*   ei  = (const int*)d_in[1];     // [2, E] row-major: src = ei, dst = ei+E
    const float* W1  = (const float*)d_in[3];
    const float* b1  = (const float*)d_in[4];
    const float* W2  = (const float*)d_in[5];
    const float* b2  = (const float*)d_in[6];
    const float* Wo  = (const float*)d_in[7];
    const float* bo  = (const float*)d_in[8];
    float* out = (float*)d_out;

    const int N = in_sizes[2];          // batch array length = N_NODES
    const int E = in_sizes[1] / 2;

    // workspace partition (256B aligned)
    size_t off = 0;
    char* base = (char*)d_ws;
    auto alloc = [&](size_t bytes) -> void* {
        off = (off + 255) & ~(size_t)255;
        void* r = base + off;
        off += bytes;
        return r;
    };
    int*   deg     = (int*)alloc((size_t)N * 4);
    int*   offsets = (int*)alloc(((size_t)N + 1) * 4);
    int*   cursor  = (int*)alloc((size_t)N * 4);
    float* dinv    = (float*)alloc((size_t)N * 4);
    int*   csr_src = (int*)alloc((size_t)E * 4);
    float* linS    = (float*)alloc((size_t)N * HID * 4);
    float* hbuf    = (float*)alloc((size_t)N * HID * 4);

    const int T = 256;
    int gN  = (N + T - 1) / T;
    int gE  = (E + T - 1) / T;
    int gNF = ((N * HID) + T - 1) / T;    // one thread per (node, feature)

    const int* src = ei;
    const int* dst = ei + E;

    // CSR build
    k_zero_i32<<<gN, T, 0, stream>>>(deg, N);
    k_hist<<<gE, T, 0, stream>>>(dst, E, deg);
    k_scan<<<1, 1024, 0, stream>>>(deg, N, offsets, cursor, dinv);
    k_scatter<<<gE, T, 0, stream>>>(src, dst, E, cursor, csr_src);

    // layer 1: x[:, -1, :] @ W1 -> aggregate -> relu
    k_lin1<<<gNF, T, 0, stream>>>(x, W1, dinv, linS, N);
    k_agg<<<gNF, T, 0, stream>>>(linS, offsets, csr_src, dinv, b1, hbuf, N);

    // layer 2: h @ W2 -> aggregate -> relu
    k_lin2<<<gNF, T, 0, stream>>>(hbuf, W2, dinv, linS, N);
    k_agg<<<gNF, T, 0, stream>>>(linS, offsets, csr_src, dinv, b2, hbuf, N);

    // output: softmax(h @ Wout + bout)
    k_out<<<gNF, T, 0, stream>>>(hbuf, Wo, bo, out, N);
}

// Round 2
// 702.305 us; speedup vs baseline: 1.3863x; 1.3863x over previous
//
#include <hip/hip_runtime.h>

#define HID 64
#define NF 5
#define NC 5

// ---------------- CSR build ----------------

__global__ void k_zero_i32(int* __restrict__ p, int n) {
    int i = blockIdx.x * blockDim.x + threadIdx.x;
    if (i < n) p[i] = 0;
}

__global__ void k_hist(const int* __restrict__ dst, int E, int* __restrict__ deg) {
    int i = blockIdx.x * blockDim.x + threadIdx.x;
    if (i < E) atomicAdd(deg + dst[i], 1);
}

// ---- 3-phase device-wide exclusive scan over deg[N] ----
// Phase A: per-block chunk sums. Block b covers [b*256*ept, (b+1)*256*ept).
__global__ __launch_bounds__(256) void k_bsum(const int* __restrict__ deg, int N, int ept,
                                              int* __restrict__ bsum) {
    __shared__ int red[256];
    int t = threadIdx.x;
    int base = (blockIdx.x * 256 + t) * ept;
    int s = 0;
    for (int k = 0; k < ept; ++k) {
        int i = base + k;
        if (i < N) s += deg[i];
    }
    red[t] = s;
    __syncthreads();
    for (int o = 128; o > 0; o >>= 1) {
        if (t < o) red[t] += red[t + o];
        __syncthreads();
    }
    if (t == 0) bsum[blockIdx.x] = red[0];
}

// Phase B: single small block scans the (<=256) block sums in place (exclusive),
// and writes offsets[N] = total.
__global__ __launch_bounds__(256) void k_bscan(int* __restrict__ bsum, int nb, int N,
                                               int* __restrict__ offsets) {
    __shared__ int s[256];
    int t = threadIdx.x;
    int v = (t < nb) ? bsum[t] : 0;
    s[t] = v;
    __syncthreads();
    for (int o = 1; o < 256; o <<= 1) {
        int u = (t >= o) ? s[t - o] : 0;
        __syncthreads();
        s[t] += u;
        __syncthreads();
    }
    if (t < nb) bsum[t] = s[t] - v;          // exclusive base per block
    if (t == 255) offsets[N] = s[255];       // grand total = E
}

// Phase C: re-read chunk, block-local exclusive scan, add block base; emit
// offsets / cursor / dinv.
__global__ __launch_bounds__(256) void k_sfin(const int* __restrict__ deg, int N, int ept,
                                              const int* __restrict__ bsum,
                                              int* __restrict__ offsets,
                                              int* __restrict__ cursor,
                                              float* __restrict__ dinv) {
    __shared__ int s[256];
    int t = threadIdx.x;
    int base = (blockIdx.x * 256 + t) * ept;
    int loc[8];                               // ept <= 8 (N <= 524288)
    int sum = 0;
    for (int k = 0; k < ept; ++k) {
        int i = base + k;
        int d = (i < N) ? deg[i] : 0;
        loc[k] = d;
        sum += d;
    }
    s[t] = sum;
    __syncthreads();
    for (int o = 1; o < 256; o <<= 1) {
        int u = (t >= o) ? s[t - o] : 0;
        __syncthreads();
        s[t] += u;
        __syncthreads();
    }
    int run = bsum[blockIdx.x] + s[t] - sum;  // global exclusive base for this thread
    for (int k = 0; k < ept; ++k) {
        int i = base + k;
        if (i < N) {
            offsets[i] = run;
            cursor[i] = run;
            dinv[i] = rsqrtf((float)loc[k] + 1.0f);
            run += loc[k];
        }
    }
}

__global__ void k_scatter(const int* __restrict__ src, const int* __restrict__ dst, int E,
                          int* __restrict__ cursor, int* __restrict__ csr_src) {
    int i = blockIdx.x * blockDim.x + threadIdx.x;
    if (i < E) {
        int d = dst[i];
        int pos = atomicAdd(cursor + d, 1);
        csr_src[pos] = src[i];
    }
}

// ---------------- GCN layers ----------------

// linS[n][f] = (sum_k x[n,3,k] * W1[k][f]) * dinv[n]
__global__ void k_lin1(const float* __restrict__ x, const float* __restrict__ W1,
                       const float* __restrict__ dinv, float* __restrict__ linS, int N) {
    int gid = blockIdx.x * blockDim.x + threadIdx.x;
    int n = gid >> 6, f = gid & 63;
    if (n >= N) return;
    const float* xr = x + (size_t)n * (4 * NF) + 3 * NF;   // x[n, 3, :]
    float acc = 0.f;
#pragma unroll
    for (int k = 0; k < NF; ++k) acc += xr[k] * W1[k * HID + f];
    linS[(size_t)n * HID + f] = acc * dinv[n];
}

// linS2[n][f] = (sum_k h[n,k] * W2[k][f]) * dinv[n]   (W2 staged in LDS)
__global__ void k_lin2(const float* __restrict__ h, const float* __restrict__ W2,
                       const float* __restrict__ dinv, float* __restrict__ linS, int N) {
    __shared__ float sW[HID * HID];
    for (int i = threadIdx.x; i < HID * HID; i += blockDim.x) sW[i] = W2[i];
    __syncthreads();
    int gid = blockIdx.x * blockDim.x + threadIdx.x;
    int n = gid >> 6, f = gid & 63;
    if (n >= N) return;
    const float* hr = h + (size_t)n * HID;
    float acc = 0.f;
#pragma unroll 8
    for (int k = 0; k < HID; ++k) acc += hr[k] * sW[k * HID + f];
    linS[(size_t)n * HID + f] = acc * dinv[n];
}

// out[d][f] = relu( dinv[d] * (linS[d][f] + sum_{e in in(d)} linS[src_e][f]) + b[f] )
__global__ void k_agg(const float* __restrict__ linS, const int* __restrict__ offsets,
                      const int* __restrict__ csr_src, const float* __restrict__ dinv,
                      const float* __restrict__ bias, float* __restrict__ out, int N) {
    int wid = (blockIdx.x * blockDim.x + threadIdx.x) >> 6;
    int f = threadIdx.x & 63;
    if (wid >= N) return;
    float acc = linS[(size_t)wid * HID + f];
    int e0 = offsets[wid], e1 = offsets[wid + 1];
    for (int e = e0; e < e1; ++e) {
        int s = csr_src[e];
        acc += linS[(size_t)s * HID + f];
    }
    float v = dinv[wid] * acc + bias[f];
    out[(size_t)wid * HID + f] = fmaxf(v, 0.f);
}

// softmax(h @ Wout + bout): one wave per node, lane = hidden index
__global__ void k_out(const float* __restrict__ h, const float* __restrict__ Wout,
                      const float* __restrict__ bout, float* __restrict__ out, int N) {
    int wid = (blockIdx.x * blockDim.x + threadIdx.x) >> 6;
    int lane = threadIdx.x & 63;
    if (wid >= N) return;
    float hv = h[(size_t)wid * HID + lane];
    float logit[NC];
#pragma unroll
    for (int c = 0; c < NC; ++c) {
        float p = hv * Wout[lane * NC + c];
#pragma unroll
        for (int o = 32; o > 0; o >>= 1) p += __shfl_xor(p, o, 64);
        logit[c] = p + bout[c];
    }
    if (lane < NC) {
        float m = logit[0];
#pragma unroll
        for (int c = 1; c < NC; ++c) m = fmaxf(m, logit[c]);
        float s = 0.f;
        float ex[NC];
#pragma unroll
        for (int c = 0; c < NC; ++c) { ex[c] = __expf(logit[c] - m); s += ex[c]; }
        out[(size_t)wid * NC + lane] = ex[lane] / s;
    }
}

// ---------------- launch ----------------

extern "C" void kernel_launch(void* const* d_in, const int* in_sizes, int n_in,
                              void* d_out, int out_size, void* d_ws, size_t ws_size,
                              hipStream_t stream) {
    const float* x   = (const float*)d_in[0];
    const int*   ei  = (const int*)d_in[1];     // [2, E]: src = ei, dst = ei+E
    const float* W1  = (const float*)d_in[3];
    const float* b1  = (const float*)d_in[4];
    const float* W2  = (const float*)d_in[5];
    const float* b2  = (const float*)d_in[6];
    const float* Wo  = (const float*)d_in[7];
    const float* bo  = (const float*)d_in[8];
    float* out = (float*)d_out;

    const int N = in_sizes[2];          // batch array length = N_NODES
    const int E = in_sizes[1] / 2;

    // workspace partition (256B aligned)
    size_t off = 0;
    char* base = (char*)d_ws;
    auto alloc = [&](size_t bytes) -> void* {
        off = (off + 255) & ~(size_t)255;
        void* r = base + off;
        off += bytes;
        return r;
    };
    int*   deg     = (int*)alloc((size_t)N * 4);
    int*   offsets = (int*)alloc(((size_t)N + 1) * 4);
    int*   cursor  = (int*)alloc((size_t)N * 4);
    float* dinv    = (float*)alloc((size_t)N * 4);
    int*   csr_src = (int*)alloc((size_t)E * 4);
    float* linS    = (float*)alloc((size_t)N * HID * 4);
    float* hbuf    = (float*)alloc((size_t)N * HID * 4);
    int*   bsum    = (int*)alloc(256 * 4);

    const int T = 256;
    int gN  = (N + T - 1) / T;
    int gE  = (E + T - 1) / T;
    int gNF = ((N * HID) + T - 1) / T;    // one thread per (node, feature)

    const int* src = ei;
    const int* dst = ei + E;

    // scan geometry: ept chosen so block count nb <= 256
    int ept = (N + 256 * 256 - 1) / (256 * 256);
    if (ept < 1) ept = 1;
    if (ept > 8) ept = 8;                 // N <= 524288 assumed
    int nb = (N + 256 * ept - 1) / (256 * ept);

    // CSR build
    k_zero_i32<<<gN, T, 0, stream>>>(deg, N);
    k_hist<<<gE, T, 0, stream>>>(dst, E, deg);
    k_bsum<<<nb, 256, 0, stream>>>(deg, N, ept, bsum);
    k_bscan<<<1, 256, 0, stream>>>(bsum, nb, N, offsets);
    k_sfin<<<nb, 256, 0, stream>>>(deg, N, ept, bsum, offsets, cursor, dinv);
    k_scatter<<<gE, T, 0, stream>>>(src, dst, E, cursor, csr_src);

    // layer 1: x[:, -1, :] @ W1 -> aggregate -> relu
    k_lin1<<<gNF, T, 0, stream>>>(x, W1, dinv, linS, N);
    k_agg<<<gNF, T, 0, stream>>>(linS, offsets, csr_src, dinv, b1, hbuf, N);

    // layer 2: h @ W2 -> aggregate -> relu
    k_lin2<<<gNF, T, 0, stream>>>(hbuf, W2, dinv, linS, N);
    k_agg<<<gNF, T, 0, stream>>>(linS, offsets, csr_src, dinv, b2, hbuf, N);

    // output: softmax(h @ Wout + bout)
    k_out<<<gNF, T, 0, stream>>>(hbuf, Wo, bo, out, N);
}

// Round 3
// 513.924 us; speedup vs baseline: 1.8944x; 1.3666x over previous
//
#include <hip/hip_runtime.h>

#define HID 64
#define NF 5
#define NC 5

// ---------------- CSR build ----------------

__global__ void k_zero_i32(int* __restrict__ p, int n) {
    int i = blockIdx.x * blockDim.x + threadIdx.x;
    if (i < n) p[i] = 0;
}

__global__ void k_hist(const int* __restrict__ dst, int E, int* __restrict__ deg) {
    int i = blockIdx.x * blockDim.x + threadIdx.x;
    if (i < E) atomicAdd(deg + dst[i], 1);
}

// ---- 3-phase device-wide exclusive scan over deg[N] ----
__global__ __launch_bounds__(256) void k_bsum(const int* __restrict__ deg, int N, int ept,
                                              int* __restrict__ bsum) {
    __shared__ int red[256];
    int t = threadIdx.x;
    int base = (blockIdx.x * 256 + t) * ept;
    int s = 0;
    for (int k = 0; k < ept; ++k) {
        int i = base + k;
        if (i < N) s += deg[i];
    }
    red[t] = s;
    __syncthreads();
    for (int o = 128; o > 0; o >>= 1) {
        if (t < o) red[t] += red[t + o];
        __syncthreads();
    }
    if (t == 0) bsum[blockIdx.x] = red[0];
}

__global__ __launch_bounds__(256) void k_bscan(int* __restrict__ bsum, int nb, int N,
                                               int* __restrict__ offsets) {
    __shared__ int s[256];
    int t = threadIdx.x;
    int v = (t < nb) ? bsum[t] : 0;
    s[t] = v;
    __syncthreads();
    for (int o = 1; o < 256; o <<= 1) {
        int u = (t >= o) ? s[t - o] : 0;
        __syncthreads();
        s[t] += u;
        __syncthreads();
    }
    if (t < nb) bsum[t] = s[t] - v;          // exclusive base per block
    if (t == 255) offsets[N] = s[255];       // grand total = E
}

__global__ __launch_bounds__(256) void k_sfin(const int* __restrict__ deg, int N, int ept,
                                              const int* __restrict__ bsum,
                                              int* __restrict__ offsets,
                                              int* __restrict__ cursor,
                                              float* __restrict__ dinv) {
    __shared__ int s[256];
    int t = threadIdx.x;
    int base = (blockIdx.x * 256 + t) * ept;
    int loc[8];                               // ept <= 8 (N <= 524288)
    int sum = 0;
    for (int k = 0; k < ept; ++k) {
        int i = base + k;
        int d = (i < N) ? deg[i] : 0;
        loc[k] = d;
        sum += d;
    }
    s[t] = sum;
    __syncthreads();
    for (int o = 1; o < 256; o <<= 1) {
        int u = (t >= o) ? s[t - o] : 0;
        __syncthreads();
        s[t] += u;
        __syncthreads();
    }
    int run = bsum[blockIdx.x] + s[t] - sum;
    for (int k = 0; k < ept; ++k) {
        int i = base + k;
        if (i < N) {
            offsets[i] = run;
            cursor[i] = run;
            dinv[i] = rsqrtf((float)loc[k] + 1.0f);
            run += loc[k];
        }
    }
}

__global__ void k_scatter(const int* __restrict__ src, const int* __restrict__ dst, int E,
                          int* __restrict__ cursor, int* __restrict__ csr_src) {
    int i = blockIdx.x * blockDim.x + threadIdx.x;
    if (i < E) {
        int d = dst[i];
        int pos = atomicAdd(cursor + d, 1);
        csr_src[pos] = src[i];
    }
}

// ---------------- GCN layers ----------------

// Layer-1 fused: out[d] = relu( dinv[d]*( L(d) + sum_{s in in(d)} L(s) ) + b1 )
// where L(n) = (x[n,3,:] @ W1) * dinv[n], recomputed per edge (20 B gather vs 256 B).
// Wave layout: g = lane>>4 picks 1 of 4 edges/iter; (lane&15)*4 is the feature quad.
__global__ __launch_bounds__(256) void k_agg1(const float* __restrict__ x,
                                              const float* __restrict__ W1,
                                              const int* __restrict__ offsets,
                                              const int* __restrict__ csr_src,
                                              const float* __restrict__ dinv,
                                              const float* __restrict__ bias,
                                              float* __restrict__ out, int N) {
    int wid = (blockIdx.x * blockDim.x + threadIdx.x) >> 6;
    int lane = threadIdx.x & 63;
    int g = lane >> 4;
    int fq = (lane & 15) << 2;
    // per-lane W1 quad in registers: w[k][j] = W1[k][fq+j]
    float w[NF][4];
#pragma unroll
    for (int k = 0; k < NF; ++k) {
        float4 t = *reinterpret_cast<const float4*>(W1 + k * HID + fq);
        w[k][0] = t.x; w[k][1] = t.y; w[k][2] = t.z; w[k][3] = t.w;
    }
    if (wid >= N) return;
    int e0 = offsets[wid], e1 = offsets[wid + 1];
    float4 acc = {0.f, 0.f, 0.f, 0.f};
    int ee = e0 + g;
    int s = (ee < e1) ? csr_src[ee] : -1;
    for (int e = e0; e < e1; e += 4) {
        int cs = s;
        int en = e + 4 + g;
        s = (en < e1) ? csr_src[en] : -1;       // prefetch next iter's index
        if (cs >= 0) {
            const float* xr = x + (size_t)cs * (4 * NF) + 3 * NF;
            float x0 = xr[0], x1 = xr[1], x2 = xr[2], x3 = xr[3], x4 = xr[4];
            float dv = dinv[cs];
            acc.x += dv * (x0*w[0][0] + x1*w[1][0] + x2*w[2][0] + x3*w[3][0] + x4*w[4][0]);
            acc.y += dv * (x0*w[0][1] + x1*w[1][1] + x2*w[2][1] + x3*w[3][1] + x4*w[4][1]);
            acc.z += dv * (x0*w[0][2] + x1*w[1][2] + x2*w[2][2] + x3*w[3][2] + x4*w[4][2]);
            acc.w += dv * (x0*w[0][3] + x1*w[1][3] + x2*w[2][3] + x3*w[3][3] + x4*w[4][3]);
        }
    }
#pragma unroll
    for (int o = 16; o < 64; o <<= 1) {
        acc.x += __shfl_xor(acc.x, o, 64);
        acc.y += __shfl_xor(acc.y, o, 64);
        acc.z += __shfl_xor(acc.z, o, 64);
        acc.w += __shfl_xor(acc.w, o, 64);
    }
    if (lane < 16) {
        const float* xr = x + (size_t)wid * (4 * NF) + 3 * NF;
        float x0 = xr[0], x1 = xr[1], x2 = xr[2], x3 = xr[3], x4 = xr[4];
        float dv = dinv[wid];
        float4 b4 = *reinterpret_cast<const float4*>(bias + fq);
        float4 r;
        float t0 = dv * (x0*w[0][0] + x1*w[1][0] + x2*w[2][0] + x3*w[3][0] + x4*w[4][0]);
        float t1 = dv * (x0*w[0][1] + x1*w[1][1] + x2*w[2][1] + x3*w[3][1] + x4*w[4][1]);
        float t2 = dv * (x0*w[0][2] + x1*w[1][2] + x2*w[2][2] + x3*w[3][2] + x4*w[4][2]);
        float t3 = dv * (x0*w[0][3] + x1*w[1][3] + x2*w[2][3] + x3*w[3][3] + x4*w[4][3]);
        r.x = fmaxf(fmaf(dv, acc.x + t0, b4.x), 0.f);
        r.y = fmaxf(fmaf(dv, acc.y + t1, b4.y), 0.f);
        r.z = fmaxf(fmaf(dv, acc.z + t2, b4.z), 0.f);
        r.w = fmaxf(fmaf(dv, acc.w + t3, b4.w), 0.f);
        *reinterpret_cast<float4*>(out + (size_t)wid * HID + fq) = r;
    }
}

// linS2[n][f] = (sum_k h[n,k] * W2[k][f]) * dinv[n]   (W2 staged in LDS)
__global__ void k_lin2(const float* __restrict__ h, const float* __restrict__ W2,
                       const float* __restrict__ dinv, float* __restrict__ linS, int N) {
    __shared__ float sW[HID * HID];
    for (int i = threadIdx.x; i < HID * HID; i += blockDim.x) sW[i] = W2[i];
    __syncthreads();
    int gid = blockIdx.x * blockDim.x + threadIdx.x;
    int n = gid >> 6, f = gid & 63;
    if (n >= N) return;
    const float* hr = h + (size_t)n * HID;
    float acc = 0.f;
#pragma unroll 8
    for (int k = 0; k < HID; ++k) acc += hr[k] * sW[k * HID + f];
    linS[(size_t)n * HID + f] = acc * dinv[n];
}

// Layer-2 aggregate: 4 edges in flight per wave, float4 per lane.
__global__ __launch_bounds__(256) void k_agg4(const float* __restrict__ linS,
                                              const int* __restrict__ offsets,
                                              const int* __restrict__ csr_src,
                                              const float* __restrict__ dinv,
                                              const float* __restrict__ bias,
                                              float* __restrict__ out, int N) {
    int wid = (blockIdx.x * blockDim.x + threadIdx.x) >> 6;
    if (wid >= N) return;
    int lane = threadIdx.x & 63;
    int g = lane >> 4;
    int fq = (lane & 15) << 2;
    int e0 = offsets[wid], e1 = offsets[wid + 1];
    float4 acc = {0.f, 0.f, 0.f, 0.f};
    int ee = e0 + g;
    int s = (ee < e1) ? csr_src[ee] : -1;
    for (int e = e0; e < e1; e += 4) {
        int cs = s;
        int en = e + 4 + g;
        s = (en < e1) ? csr_src[en] : -1;       // prefetch next iter's index
        if (cs >= 0) {
            float4 v = *reinterpret_cast<const float4*>(linS + (size_t)cs * HID + fq);
            acc.x += v.x; acc.y += v.y; acc.z += v.z; acc.w += v.w;
        }
    }
#pragma unroll
    for (int o = 16; o < 64; o <<= 1) {
        acc.x += __shfl_xor(acc.x, o, 64);
        acc.y += __shfl_xor(acc.y, o, 64);
        acc.z += __shfl_xor(acc.z, o, 64);
        acc.w += __shfl_xor(acc.w, o, 64);
    }
    if (lane < 16) {
        float4 self = *reinterpret_cast<const float4*>(linS + (size_t)wid * HID + fq);
        float4 b4 = *reinterpret_cast<const float4*>(bias + fq);
        float dv = dinv[wid];
        float4 r;
        r.x = fmaxf(fmaf(dv, acc.x + self.x, b4.x), 0.f);
        r.y = fmaxf(fmaf(dv, acc.y + self.y, b4.y), 0.f);
        r.z = fmaxf(fmaf(dv, acc.z + self.z, b4.z), 0.f);
        r.w = fmaxf(fmaf(dv, acc.w + self.w, b4.w), 0.f);
        *reinterpret_cast<float4*>(out + (size_t)wid * HID + fq) = r;
    }
}

// softmax(h @ Wout + bout): one wave per node, lane = hidden index
__global__ void k_out(const float* __restrict__ h, const float* __restrict__ Wout,
                      const float* __restrict__ bout, float* __restrict__ out, int N) {
    int wid = (blockIdx.x * blockDim.x + threadIdx.x) >> 6;
    int lane = threadIdx.x & 63;
    if (wid >= N) return;
    float hv = h[(size_t)wid * HID + lane];
    float logit[NC];
#pragma unroll
    for (int c = 0; c < NC; ++c) {
        float p = hv * Wout[lane * NC + c];
#pragma unroll
        for (int o = 32; o > 0; o >>= 1) p += __shfl_xor(p, o, 64);
        logit[c] = p + bout[c];
    }
    if (lane < NC) {
        float m = logit[0];
#pragma unroll
        for (int c = 1; c < NC; ++c) m = fmaxf(m, logit[c]);
        float s = 0.f;
        float ex[NC];
#pragma unroll
        for (int c = 0; c < NC; ++c) { ex[c] = __expf(logit[c] - m); s += ex[c]; }
        out[(size_t)wid * NC + lane] = ex[lane] / s;
    }
}

// ---------------- launch ----------------

extern "C" void kernel_launch(void* const* d_in, const int* in_sizes, int n_in,
                              void* d_out, int out_size, void* d_ws, size_t ws_size,
                              hipStream_t stream) {
    const float* x   = (const float*)d_in[0];
    const int*   ei  = (const int*)d_in[1];     // [2, E]: src = ei, dst = ei+E
    const float* W1  = (const float*)d_in[3];
    const float* b1  = (const float*)d_in[4];
    const float* W2  = (const float*)d_in[5];
    const float* b2  = (const float*)d_in[6];
    const float* Wo  = (const float*)d_in[7];
    const float* bo  = (const float*)d_in[8];
    float* out = (float*)d_out;

    const int N = in_sizes[2];          // batch array length = N_NODES
    const int E = in_sizes[1] / 2;

    // workspace partition (256B aligned)
    size_t off = 0;
    char* base = (char*)d_ws;
    auto alloc = [&](size_t bytes) -> void* {
        off = (off + 255) & ~(size_t)255;
        void* r = base + off;
        off += bytes;
        return r;
    };
    int*   deg     = (int*)alloc((size_t)N * 4);
    int*   offsets = (int*)alloc(((size_t)N + 1) * 4);
    int*   cursor  = (int*)alloc((size_t)N * 4);
    float* dinv    = (float*)alloc((size_t)N * 4);
    int*   csr_src = (int*)alloc((size_t)E * 4);
    float* linS    = (float*)alloc((size_t)N * HID * 4);
    float* hbuf    = (float*)alloc((size_t)N * HID * 4);
    int*   bsum    = (int*)alloc(256 * 4);

    const int T = 256;
    int gN  = (N + T - 1) / T;
    int gE  = (E + T - 1) / T;
    int gNF = ((N * HID) + T - 1) / T;    // one wave per node (4 waves/block)

    const int* src = ei;
    const int* dst = ei + E;

    // scan geometry
    int ept = (N + 256 * 256 - 1) / (256 * 256);
    if (ept < 1) ept = 1;
    if (ept > 8) ept = 8;
    int nb = (N + 256 * ept - 1) / (256 * ept);

    // CSR build
    k_zero_i32<<<gN, T, 0, stream>>>(deg, N);
    k_hist<<<gE, T, 0, stream>>>(dst, E, deg);
    k_bsum<<<nb, 256, 0, stream>>>(deg, N, ept, bsum);
    k_bscan<<<1, 256, 0, stream>>>(bsum, nb, N, offsets);
    k_sfin<<<nb, 256, 0, stream>>>(deg, N, ept, bsum, offsets, cursor, dinv);
    k_scatter<<<gE, T, 0, stream>>>(src, dst, E, cursor, csr_src);

    // layer 1: fused (x[:,-1,:] @ W1)*dinv recompute-per-edge aggregate + relu
    k_agg1<<<gNF, T, 0, stream>>>(x, W1, offsets, csr_src, dinv, b1, hbuf, N);

    // layer 2: h @ W2 -> aggregate -> relu
    k_lin2<<<gNF, T, 0, stream>>>(hbuf, W2, dinv, linS, N);
    k_agg4<<<gNF, T, 0, stream>>>(linS, offsets, csr_src, dinv, b2, hbuf, N);

    // output: softmax(h @ Wout + bout)
    k_out<<<gNF, T, 0, stream>>>(hbuf, Wo, bo, out, N);
}

// Round 4
// 386.234 us; speedup vs baseline: 2.5207x; 1.3306x over previous
//
#include <hip/hip_runtime.h>

#define HID 64
#define NF 5
#define NC 5

#define WSH 8                 // window shift: 256 nodes per window
#define WINN 256              // nodes per window (== blockDim of k_csr)
#define NBMAX 512             // max windows supported (N <= 131072)
#define SRCB 17               // bits for src in packed pair (N <= 131072)
#define NBLK_FILL 160         // blocks for bcount/bfill (big chunks -> long write runs)

__global__ void k_zero_i32(int* __restrict__ p, int n) {
    int i = blockIdx.x * blockDim.x + threadIdx.x;
    if (i < n) p[i] = 0;
}

// ---------------- bucketed CSR build ----------------

// Pass 1: per-bucket edge counts (LDS histogram per block, one flush atomic per bucket)
__global__ __launch_bounds__(256) void k_bcount(const int* __restrict__ dst, int E, int chunk,
                                                int nb, int* __restrict__ bcount) {
    __shared__ int cnt[NBMAX];
    for (int i = threadIdx.x; i < nb; i += 256) cnt[i] = 0;
    __syncthreads();
    int c0 = blockIdx.x * chunk;
    int c1 = c0 + chunk; if (c1 > E) c1 = E;
    for (int i = c0 + threadIdx.x; i < c1; i += 256)
        atomicAdd(&cnt[dst[i] >> WSH], 1);
    __syncthreads();
    for (int i = threadIdx.x; i < nb; i += 256) {
        int v = cnt[i];
        if (v) atomicAdd(&bcount[i], v);
    }
}

// Pass 2: exclusive scan of bucket counts -> bbase / bcursor; offsets[N] = E.
__global__ __launch_bounds__(512) void k_bscan2(const int* __restrict__ bcount, int nb, int N,
                                                int* __restrict__ bbase, int* __restrict__ bcursor,
                                                int* __restrict__ offsets) {
    __shared__ int s[512];
    int t = threadIdx.x;
    int v = (t < nb) ? bcount[t] : 0;
    s[t] = v;
    __syncthreads();
    for (int o = 1; o < 512; o <<= 1) {
        int u = (t >= o) ? s[t - o] : 0;
        __syncthreads();
        s[t] += u;
        __syncthreads();
    }
    if (t < nb) { bbase[t] = s[t] - v; bcursor[t] = s[t] - v; }
    if (t == nb - 1) { bbase[nb] = s[t]; offsets[N] = s[t]; }
}

// Pass 3: partition edges into bucket-contiguous pair regions.
// Each block: LDS-count its chunk per bucket, claim space (1 atomic per bucket),
// then write packed pairs (dstLocal<<SRCB | src) in dense per-bucket runs.
__global__ __launch_bounds__(256) void k_bfill(const int* __restrict__ src,
                                               const int* __restrict__ dst, int E, int chunk,
                                               int nb, int* __restrict__ bcursor,
                                               unsigned int* __restrict__ pairbuf) {
    __shared__ int cnt[NBMAX];
    __shared__ int wcur[NBMAX];
    for (int i = threadIdx.x; i < nb; i += 256) cnt[i] = 0;
    __syncthreads();
    int c0 = blockIdx.x * chunk;
    int c1 = c0 + chunk; if (c1 > E) c1 = E;
    for (int i = c0 + threadIdx.x; i < c1; i += 256)
        atomicAdd(&cnt[dst[i] >> WSH], 1);
    __syncthreads();
    for (int i = threadIdx.x; i < nb; i += 256) {
        int v = cnt[i];
        wcur[i] = v ? atomicAdd(&bcursor[i], v) : 0;
    }
    __syncthreads();
    for (int i = c0 + threadIdx.x; i < c1; i += 256) {
        int d = dst[i];
        int b = d >> WSH;
        int p = atomicAdd(&wcur[b], 1);
        pairbuf[p] = ((unsigned)(d & (WINN - 1)) << SRCB) | (unsigned)src[i];
    }
}

// Pass 4: one block per window. Exclusive ownership of pair region == CSR region.
// Produces deg->dinv, offsets, and csr_src, all with block-local (single-CU) writes.
__global__ __launch_bounds__(WINN) void k_csr(const unsigned int* __restrict__ pairbuf,
                                              const int* __restrict__ bbase, int N,
                                              int* __restrict__ offsets,
                                              int* __restrict__ csr_src,
                                              float* __restrict__ dinv) {
    int b = blockIdx.x, t = threadIdx.x;
    int winStart = b << WSH;
    int rbeg = bbase[b], rend = bbase[b + 1];
    __shared__ int deg[WINN];
    __shared__ int cur[WINN];
    __shared__ int s[WINN];
    deg[t] = 0;
    __syncthreads();
    for (int p = rbeg + t; p < rend; p += WINN)
        atomicAdd(&deg[pairbuf[p] >> SRCB], 1);
    __syncthreads();
    int v = deg[t];
    s[t] = v;
    __syncthreads();
    for (int o = 1; o < WINN; o <<= 1) {
        int u = (t >= o) ? s[t - o] : 0;
        __syncthreads();
        s[t] += u;
        __syncthreads();
    }
    int node = winStart + t;
    if (node < N) {
        int base = rbeg + s[t] - v;
        offsets[node] = base;
        cur[t] = base;
        dinv[node] = rsqrtf((float)v + 1.0f);
    }
    __syncthreads();
    for (int p = rbeg + t; p < rend; p += WINN) {
        unsigned u = pairbuf[p];
        int dl = u >> SRCB;
        int sn = u & ((1u << SRCB) - 1);
        int pos = atomicAdd(&cur[dl], 1);
        csr_src[pos] = sn;
    }
}

// ---------------- GCN layers ----------------

// Layer-1 fused: out[d] = relu( dinv[d]*( L(d) + sum_{s in in(d)} L(s) ) + b1 )
// where L(n) = (x[n,3,:] @ W1) * dinv[n], recomputed per edge (24 B gather vs 256 B).
__global__ __launch_bounds__(256) void k_agg1(const float* __restrict__ x,
                                              const float* __restrict__ W1,
                                              const int* __restrict__ offsets,
                                              const int* __restrict__ csr_src,
                                              const float* __restrict__ dinv,
                                              const float* __restrict__ bias,
                                              float* __restrict__ out, int N) {
    int wid = (blockIdx.x * blockDim.x + threadIdx.x) >> 6;
    int lane = threadIdx.x & 63;
    int g = lane >> 4;
    int fq = (lane & 15) << 2;
    float w[NF][4];
#pragma unroll
    for (int k = 0; k < NF; ++k) {
        float4 t = *reinterpret_cast<const float4*>(W1 + k * HID + fq);
        w[k][0] = t.x; w[k][1] = t.y; w[k][2] = t.z; w[k][3] = t.w;
    }
    if (wid >= N) return;
    int e0 = offsets[wid], e1 = offsets[wid + 1];
    float4 acc = {0.f, 0.f, 0.f, 0.f};
    int ee = e0 + g;
    int s = (ee < e1) ? csr_src[ee] : -1;
    for (int e = e0; e < e1; e += 4) {
        int cs = s;
        int en = e + 4 + g;
        s = (en < e1) ? csr_src[en] : -1;       // prefetch next iter's index
        if (cs >= 0) {
            const float* xr = x + (size_t)cs * (4 * NF) + 3 * NF;
            float x0 = xr[0], x1 = xr[1], x2 = xr[2], x3 = xr[3], x4 = xr[4];
            float dv = dinv[cs];
            acc.x += dv * (x0*w[0][0] + x1*w[1][0] + x2*w[2][0] + x3*w[3][0] + x4*w[4][0]);
            acc.y += dv * (x0*w[0][1] + x1*w[1][1] + x2*w[2][1] + x3*w[3][1] + x4*w[4][1]);
            acc.z += dv * (x0*w[0][2] + x1*w[1][2] + x2*w[2][2] + x3*w[3][2] + x4*w[4][2]);
            acc.w += dv * (x0*w[0][3] + x1*w[1][3] + x2*w[2][3] + x3*w[3][3] + x4*w[4][3]);
        }
    }
#pragma unroll
    for (int o = 16; o < 64; o <<= 1) {
        acc.x += __shfl_xor(acc.x, o, 64);
        acc.y += __shfl_xor(acc.y, o, 64);
        acc.z += __shfl_xor(acc.z, o, 64);
        acc.w += __shfl_xor(acc.w, o, 64);
    }
    if (lane < 16) {
        const float* xr = x + (size_t)wid * (4 * NF) + 3 * NF;
        float x0 = xr[0], x1 = xr[1], x2 = xr[2], x3 = xr[3], x4 = xr[4];
        float dv = dinv[wid];
        float4 b4 = *reinterpret_cast<const float4*>(bias + fq);
        float4 r;
        float t0 = dv * (x0*w[0][0] + x1*w[1][0] + x2*w[2][0] + x3*w[3][0] + x4*w[4][0]);
        float t1 = dv * (x0*w[0][1] + x1*w[1][1] + x2*w[2][1] + x3*w[3][1] + x4*w[4][1]);
        float t2 = dv * (x0*w[0][2] + x1*w[1][2] + x2*w[2][2] + x3*w[3][2] + x4*w[4][2]);
        float t3 = dv * (x0*w[0][3] + x1*w[1][3] + x2*w[2][3] + x3*w[3][3] + x4*w[4][3]);
        r.x = fmaxf(fmaf(dv, acc.x + t0, b4.x), 0.f);
        r.y = fmaxf(fmaf(dv, acc.y + t1, b4.y), 0.f);
        r.z = fmaxf(fmaf(dv, acc.z + t2, b4.z), 0.f);
        r.w = fmaxf(fmaf(dv, acc.w + t3, b4.w), 0.f);
        *reinterpret_cast<float4*>(out + (size_t)wid * HID + fq) = r;
    }
}

// linS2[n][f] = (sum_k h[n,k] * W2[k][f]) * dinv[n]   (W2 staged in LDS)
__global__ void k_lin2(const float* __restrict__ h, const float* __restrict__ W2,
                       const float* __restrict__ dinv, float* __restrict__ linS, int N) {
    __shared__ float sW[HID * HID];
    for (int i = threadIdx.x; i < HID * HID; i += blockDim.x) sW[i] = W2[i];
    __syncthreads();
    int gid = blockIdx.x * blockDim.x + threadIdx.x;
    int n = gid >> 6, f = gid & 63;
    if (n >= N) return;
    const float* hr = h + (size_t)n * HID;
    float acc = 0.f;
#pragma unroll 8
    for (int k = 0; k < HID; ++k) acc += hr[k] * sW[k * HID + f];
    linS[(size_t)n * HID + f] = acc * dinv[n];
}

// Layer-2 aggregate: 4 edges in flight per wave, float4 per lane.
__global__ __launch_bounds__(256) void k_agg4(const float* __restrict__ linS,
                                              const int* __restrict__ offsets,
                                              const int* __restrict__ csr_src,
                                              const float* __restrict__ dinv,
                                              const float* __restrict__ bias,
                                              float* __restrict__ out, int N) {
    int wid = (blockIdx.x * blockDim.x + threadIdx.x) >> 6;
    if (wid >= N) return;
    int lane = threadIdx.x & 63;
    int g = lane >> 4;
    int fq = (lane & 15) << 2;
    int e0 = offsets[wid], e1 = offsets[wid + 1];
    float4 acc = {0.f, 0.f, 0.f, 0.f};
    int ee = e0 + g;
    int s = (ee < e1) ? csr_src[ee] : -1;
    for (int e = e0; e < e1; e += 4) {
        int cs = s;
        int en = e + 4 + g;
        s = (en < e1) ? csr_src[en] : -1;       // prefetch next iter's index
        if (cs >= 0) {
            float4 v = *reinterpret_cast<const float4*>(linS + (size_t)cs * HID + fq);
            acc.x += v.x; acc.y += v.y; acc.z += v.z; acc.w += v.w;
        }
    }
#pragma unroll
    for (int o = 16; o < 64; o <<= 1) {
        acc.x += __shfl_xor(acc.x, o, 64);
        acc.y += __shfl_xor(acc.y, o, 64);
        acc.z += __shfl_xor(acc.z, o, 64);
        acc.w += __shfl_xor(acc.w, o, 64);
    }
    if (lane < 16) {
        float4 self = *reinterpret_cast<const float4*>(linS + (size_t)wid * HID + fq);
        float4 b4 = *reinterpret_cast<const float4*>(bias + fq);
        float dv = dinv[wid];
        float4 r;
        r.x = fmaxf(fmaf(dv, acc.x + self.x, b4.x), 0.f);
        r.y = fmaxf(fmaf(dv, acc.y + self.y, b4.y), 0.f);
        r.z = fmaxf(fmaf(dv, acc.z + self.z, b4.z), 0.f);
        r.w = fmaxf(fmaf(dv, acc.w + self.w, b4.w), 0.f);
        *reinterpret_cast<float4*>(out + (size_t)wid * HID + fq) = r;
    }
}

// softmax(h @ Wout + bout): one wave per node, lane = hidden index
__global__ void k_out(const float* __restrict__ h, const float* __restrict__ Wout,
                      const float* __restrict__ bout, float* __restrict__ out, int N) {
    int wid = (blockIdx.x * blockDim.x + threadIdx.x) >> 6;
    int lane = threadIdx.x & 63;
    if (wid >= N) return;
    float hv = h[(size_t)wid * HID + lane];
    float logit[NC];
#pragma unroll
    for (int c = 0; c < NC; ++c) {
        float p = hv * Wout[lane * NC + c];
#pragma unroll
        for (int o = 32; o > 0; o >>= 1) p += __shfl_xor(p, o, 64);
        logit[c] = p + bout[c];
    }
    if (lane < NC) {
        float m = logit[0];
#pragma unroll
        for (int c = 1; c < NC; ++c) m = fmaxf(m, logit[c]);
        float s = 0.f;
        float ex[NC];
#pragma unroll
        for (int c = 0; c < NC; ++c) { ex[c] = __expf(logit[c] - m); s += ex[c]; }
        out[(size_t)wid * NC + lane] = ex[lane] / s;
    }
}

// ---------------- launch ----------------

extern "C" void kernel_launch(void* const* d_in, const int* in_sizes, int n_in,
                              void* d_out, int out_size, void* d_ws, size_t ws_size,
                              hipStream_t stream) {
    const float* x   = (const float*)d_in[0];
    const int*   ei  = (const int*)d_in[1];     // [2, E]: src = ei, dst = ei+E
    const float* W1  = (const float*)d_in[3];
    const float* b1  = (const float*)d_in[4];
    const float* W2  = (const float*)d_in[5];
    const float* b2  = (const float*)d_in[6];
    const float* Wo  = (const float*)d_in[7];
    const float* bo  = (const float*)d_in[8];
    float* out = (float*)d_out;

    const int N = in_sizes[2];          // batch array length = N_NODES (assumed <= 131072)
    const int E = in_sizes[1] / 2;

    // workspace partition (256B aligned)
    size_t off = 0;
    char* base = (char*)d_ws;
    auto alloc = [&](size_t bytes) -> void* {
        off = (off + 255) & ~(size_t)255;
        void* r = base + off;
        off += bytes;
        return r;
    };
    int*      bcount  = (int*)alloc((size_t)NBMAX * 4);
    int*      bbase   = (int*)alloc(((size_t)NBMAX + 1) * 4);
    int*      bcursor = (int*)alloc((size_t)NBMAX * 4);
    unsigned* pairbuf = (unsigned*)alloc((size_t)E * 4);
    int*      offsets = (int*)alloc(((size_t)N + 1) * 4);
    int*      csr_src = (int*)alloc((size_t)E * 4);
    float*    dinv    = (float*)alloc((size_t)N * 4);
    float*    linS    = (float*)alloc((size_t)N * HID * 4);
    float*    hbuf    = (float*)alloc((size_t)N * HID * 4);

    const int T = 256;
    int gNF = ((N * HID) + T - 1) / T;    // one wave per node (4 waves/block)

    const int* src = ei;
    const int* dst = ei + E;

    int nb = (N + WINN - 1) >> WSH;                    // number of windows/buckets
    int chunk = (E + NBLK_FILL - 1) / NBLK_FILL;       // edges per fill block

    // bucketed CSR build
    k_zero_i32<<<(nb + 255) / 256, 256, 0, stream>>>(bcount, nb);
    k_bcount<<<NBLK_FILL, 256, 0, stream>>>(dst, E, chunk, nb, bcount);
    k_bscan2<<<1, 512, 0, stream>>>(bcount, nb, N, bbase, bcursor, offsets);
    k_bfill<<<NBLK_FILL, 256, 0, stream>>>(src, dst, E, chunk, nb, bcursor, pairbuf);
    k_csr<<<nb, WINN, 0, stream>>>(pairbuf, bbase, N, offsets, csr_src, dinv);

    // layer 1: fused (x[:,-1,:] @ W1)*dinv recompute-per-edge aggregate + relu
    k_agg1<<<gNF, T, 0, stream>>>(x, W1, offsets, csr_src, dinv, b1, hbuf, N);

    // layer 2: h @ W2 -> aggregate -> relu
    k_lin2<<<gNF, T, 0, stream>>>(hbuf, W2, dinv, linS, N);
    k_agg4<<<gNF, T, 0, stream>>>(linS, offsets, csr_src, dinv, b2, hbuf, N);

    // output: softmax(h @ Wout + bout)
    k_out<<<gNF, T, 0, stream>>>(hbuf, Wo, bo, out, N);
}

// Round 5
// 298.633 us; speedup vs baseline: 3.2601x; 1.2933x over previous
//
#include <hip/hip_runtime.h>

#define HID 64
#define NF 5
#define NC 5

#define WSH 8                 // window shift: 256 nodes per window
#define WINN 256              // nodes per window (== blockDim of k_csr)
#define NBMAX 512             // max windows supported (N <= 131072)
#define SRCB 17               // bits for src in packed pair (N <= 131072)
#define NBLK_FILL 160         // blocks for bcount/bfill (big chunks -> long write runs)

__global__ void k_zero_i32(int* __restrict__ p, int n) {
    int i = blockIdx.x * blockDim.x + threadIdx.x;
    if (i < n) p[i] = 0;
}

// ---------------- bucketed CSR build ----------------

__global__ __launch_bounds__(256) void k_bcount(const int* __restrict__ dst, int E, int chunk,
                                                int nb, int* __restrict__ bcount) {
    __shared__ int cnt[NBMAX];
    for (int i = threadIdx.x; i < nb; i += 256) cnt[i] = 0;
    __syncthreads();
    int c0 = blockIdx.x * chunk;
    int c1 = c0 + chunk; if (c1 > E) c1 = E;
    for (int i = c0 + threadIdx.x; i < c1; i += 256)
        atomicAdd(&cnt[dst[i] >> WSH], 1);
    __syncthreads();
    for (int i = threadIdx.x; i < nb; i += 256) {
        int v = cnt[i];
        if (v) atomicAdd(&bcount[i], v);
    }
}

__global__ __launch_bounds__(512) void k_bscan2(const int* __restrict__ bcount, int nb, int N,
                                                int* __restrict__ bbase, int* __restrict__ bcursor,
                                                int* __restrict__ offsets) {
    __shared__ int s[512];
    int t = threadIdx.x;
    int v = (t < nb) ? bcount[t] : 0;
    s[t] = v;
    __syncthreads();
    for (int o = 1; o < 512; o <<= 1) {
        int u = (t >= o) ? s[t - o] : 0;
        __syncthreads();
        s[t] += u;
        __syncthreads();
    }
    if (t < nb) { bbase[t] = s[t] - v; bcursor[t] = s[t] - v; }
    if (t == nb - 1) { bbase[nb] = s[t]; offsets[N] = s[t]; }
}

__global__ __launch_bounds__(256) void k_bfill(const int* __restrict__ src,
                                               const int* __restrict__ dst, int E, int chunk,
                                               int nb, int* __restrict__ bcursor,
                                               unsigned int* __restrict__ pairbuf) {
    __shared__ int cnt[NBMAX];
    __shared__ int wcur[NBMAX];
    for (int i = threadIdx.x; i < nb; i += 256) cnt[i] = 0;
    __syncthreads();
    int c0 = blockIdx.x * chunk;
    int c1 = c0 + chunk; if (c1 > E) c1 = E;
    for (int i = c0 + threadIdx.x; i < c1; i += 256)
        atomicAdd(&cnt[dst[i] >> WSH], 1);
    __syncthreads();
    for (int i = threadIdx.x; i < nb; i += 256) {
        int v = cnt[i];
        wcur[i] = v ? atomicAdd(&bcursor[i], v) : 0;
    }
    __syncthreads();
    for (int i = c0 + threadIdx.x; i < c1; i += 256) {
        int d = dst[i];
        int b = d >> WSH;
        int p = atomicAdd(&wcur[b], 1);
        pairbuf[p] = ((unsigned)(d & (WINN - 1)) << SRCB) | (unsigned)src[i];
    }
}

__global__ __launch_bounds__(WINN) void k_csr(const unsigned int* __restrict__ pairbuf,
                                              const int* __restrict__ bbase, int N,
                                              int* __restrict__ offsets,
                                              int* __restrict__ csr_src,
                                              float* __restrict__ dinv) {
    int b = blockIdx.x, t = threadIdx.x;
    int winStart = b << WSH;
    int rbeg = bbase[b], rend = bbase[b + 1];
    __shared__ int deg[WINN];
    __shared__ int cur[WINN];
    __shared__ int s[WINN];
    deg[t] = 0;
    __syncthreads();
    for (int p = rbeg + t; p < rend; p += WINN)
        atomicAdd(&deg[pairbuf[p] >> SRCB], 1);
    __syncthreads();
    int v = deg[t];
    s[t] = v;
    __syncthreads();
    for (int o = 1; o < WINN; o <<= 1) {
        int u = (t >= o) ? s[t - o] : 0;
        __syncthreads();
        s[t] += u;
        __syncthreads();
    }
    int node = winStart + t;
    if (node < N) {
        int base = rbeg + s[t] - v;
        offsets[node] = base;
        cur[t] = base;
        dinv[node] = rsqrtf((float)v + 1.0f);
    }
    __syncthreads();
    for (int p = rbeg + t; p < rend; p += WINN) {
        unsigned u = pairbuf[p];
        int dl = u >> SRCB;
        int sn = u & ((1u << SRCB) - 1);
        int pos = atomicAdd(&cur[dl], 1);
        csr_src[pos] = sn;
    }
}

// ---------------- GCN layers ----------------

// Layer-1 fused, now emitting g1[d] = relu( dinv[d]*( L(d)+Σ L(s) ) + b1 ) * dinv[d]
// where L(n) = (x[n,3,:] @ W1) * dinv[n] recomputed per edge.
__global__ __launch_bounds__(256) void k_agg1(const float* __restrict__ x,
                                              const float* __restrict__ W1,
                                              const int* __restrict__ offsets,
                                              const int* __restrict__ csr_src,
                                              const float* __restrict__ dinv,
                                              const float* __restrict__ bias,
                                              float* __restrict__ out, int N) {
    int wid = (blockIdx.x * blockDim.x + threadIdx.x) >> 6;
    int lane = threadIdx.x & 63;
    int g = lane >> 4;
    int fq = (lane & 15) << 2;
    float w[NF][4];
#pragma unroll
    for (int k = 0; k < NF; ++k) {
        float4 t = *reinterpret_cast<const float4*>(W1 + k * HID + fq);
        w[k][0] = t.x; w[k][1] = t.y; w[k][2] = t.z; w[k][3] = t.w;
    }
    if (wid >= N) return;
    int e0 = offsets[wid], e1 = offsets[wid + 1];
    float4 acc = {0.f, 0.f, 0.f, 0.f};
    int ee = e0 + g;
    int s = (ee < e1) ? csr_src[ee] : -1;
    for (int e = e0; e < e1; e += 4) {
        int cs = s;
        int en = e + 4 + g;
        s = (en < e1) ? csr_src[en] : -1;       // prefetch next iter's index
        if (cs >= 0) {
            const float* xr = x + (size_t)cs * (4 * NF) + 3 * NF;
            float x0 = xr[0], x1 = xr[1], x2 = xr[2], x3 = xr[3], x4 = xr[4];
            float dv = dinv[cs];
            acc.x += dv * (x0*w[0][0] + x1*w[1][0] + x2*w[2][0] + x3*w[3][0] + x4*w[4][0]);
            acc.y += dv * (x0*w[0][1] + x1*w[1][1] + x2*w[2][1] + x3*w[3][1] + x4*w[4][1]);
            acc.z += dv * (x0*w[0][2] + x1*w[1][2] + x2*w[2][2] + x3*w[3][2] + x4*w[4][2]);
            acc.w += dv * (x0*w[0][3] + x1*w[1][3] + x2*w[2][3] + x3*w[3][3] + x4*w[4][3]);
        }
    }
#pragma unroll
    for (int o = 16; o < 64; o <<= 1) {
        acc.x += __shfl_xor(acc.x, o, 64);
        acc.y += __shfl_xor(acc.y, o, 64);
        acc.z += __shfl_xor(acc.z, o, 64);
        acc.w += __shfl_xor(acc.w, o, 64);
    }
    if (lane < 16) {
        const float* xr = x + (size_t)wid * (4 * NF) + 3 * NF;
        float x0 = xr[0], x1 = xr[1], x2 = xr[2], x3 = xr[3], x4 = xr[4];
        float dv = dinv[wid];
        float4 b4 = *reinterpret_cast<const float4*>(bias + fq);
        float4 r;
        float t0 = dv * (x0*w[0][0] + x1*w[1][0] + x2*w[2][0] + x3*w[3][0] + x4*w[4][0]);
        float t1 = dv * (x0*w[0][1] + x1*w[1][1] + x2*w[2][1] + x3*w[3][1] + x4*w[4][1]);
        float t2 = dv * (x0*w[0][2] + x1*w[1][2] + x2*w[2][2] + x3*w[3][2] + x4*w[4][2]);
        float t3 = dv * (x0*w[0][3] + x1*w[1][3] + x2*w[2][3] + x3*w[3][3] + x4*w[4][3]);
        // g1 = relu(layer1_out) * dinv  (so layer-2 aggregation runs pre-matmul)
        r.x = fmaxf(fmaf(dv, acc.x + t0, b4.x), 0.f) * dv;
        r.y = fmaxf(fmaf(dv, acc.y + t1, b4.y), 0.f) * dv;
        r.z = fmaxf(fmaf(dv, acc.z + t2, b4.z), 0.f) * dv;
        r.w = fmaxf(fmaf(dv, acc.w + t3, b4.w), 0.f) * dv;
        *reinterpret_cast<float4*>(out + (size_t)wid * HID + fq) = r;
    }
}

// Layer-2 pre-matmul aggregate: aggH[d] = dinv[d]*( g1[d] + Σ_s g1[s] )
__global__ __launch_bounds__(256) void k_aggG(const float* __restrict__ g1,
                                              const int* __restrict__ offsets,
                                              const int* __restrict__ csr_src,
                                              const float* __restrict__ dinv,
                                              float* __restrict__ aggH, int N) {
    int wid = (blockIdx.x * blockDim.x + threadIdx.x) >> 6;
    if (wid >= N) return;
    int lane = threadIdx.x & 63;
    int g = lane >> 4;
    int fq = (lane & 15) << 2;
    int e0 = offsets[wid], e1 = offsets[wid + 1];
    float4 acc = {0.f, 0.f, 0.f, 0.f};
    int ee = e0 + g;
    int s = (ee < e1) ? csr_src[ee] : -1;
    for (int e = e0; e < e1; e += 4) {
        int cs = s;
        int en = e + 4 + g;
        s = (en < e1) ? csr_src[en] : -1;       // prefetch next iter's index
        if (cs >= 0) {
            float4 v = *reinterpret_cast<const float4*>(g1 + (size_t)cs * HID + fq);
            acc.x += v.x; acc.y += v.y; acc.z += v.z; acc.w += v.w;
        }
    }
#pragma unroll
    for (int o = 16; o < 64; o <<= 1) {
        acc.x += __shfl_xor(acc.x, o, 64);
        acc.y += __shfl_xor(acc.y, o, 64);
        acc.z += __shfl_xor(acc.z, o, 64);
        acc.w += __shfl_xor(acc.w, o, 64);
    }
    if (lane < 16) {
        float4 self = *reinterpret_cast<const float4*>(g1 + (size_t)wid * HID + fq);
        float dv = dinv[wid];
        float4 r;
        r.x = dv * (acc.x + self.x);
        r.y = dv * (acc.y + self.y);
        r.z = dv * (acc.z + self.z);
        r.w = dv * (acc.w + self.w);
        *reinterpret_cast<float4*>(aggH + (size_t)wid * HID + fq) = r;
    }
}

// Fused tail: H2 = relu(aggH @ W2 + b2); out = softmax(H2 @ Wout + bout).
// 64-node tile per block; thread (ty=tx>>4, txl=tx&15) owns 4 nodes x 4 features.
__global__ __launch_bounds__(256) void k_fuse(const float* __restrict__ aggH,
                                              const float* __restrict__ W2,
                                              const float* __restrict__ b2,
                                              const float* __restrict__ Wout,
                                              const float* __restrict__ bout,
                                              float* __restrict__ out, int N) {
    __shared__ float4 sh4[64][17];      // aggH tile, padded (bank-spread)
    __shared__ float4 sW4[64 * 16];     // W2 row-major float4 quads
    __shared__ float  swout[64][NC];
    __shared__ float  sb2[64];
    __shared__ float  sbout[8];
    int tx = threadIdx.x;
    int nb0 = blockIdx.x * 64;

    const float4* W2_4 = reinterpret_cast<const float4*>(W2);
    for (int i = tx; i < 64 * 16; i += 256) sW4[i] = W2_4[i];
    const float4* aggH4 = reinterpret_cast<const float4*>(aggH);
    for (int i = tx; i < 64 * 16; i += 256) {
        int row = i >> 4, c4 = i & 15;
        int node = nb0 + row;
        float4 v = {0.f, 0.f, 0.f, 0.f};
        if (node < N) v = aggH4[(size_t)node * 16 + c4];
        sh4[row][c4] = v;
    }
    if (tx < 64) sb2[tx] = b2[tx];
    for (int i = tx; i < 64 * NC; i += 256) swout[i / NC][i % NC] = Wout[i];
    if (tx < NC) sbout[tx] = bout[tx];
    __syncthreads();

    int ty = tx >> 4;       // local node group: rows ty*4 .. ty*4+3
    int txl = tx & 15;      // feature quad: f = txl*4 .. txl*4+3

    float acc[4][4];
#pragma unroll
    for (int j = 0; j < 4; ++j)
#pragma unroll
        for (int i = 0; i < 4; ++i) acc[j][i] = 0.f;

    for (int k4 = 0; k4 < 16; ++k4) {
        float4 w0 = sW4[(k4 * 4 + 0) * 16 + txl];
        float4 w1 = sW4[(k4 * 4 + 1) * 16 + txl];
        float4 w2 = sW4[(k4 * 4 + 2) * 16 + txl];
        float4 w3 = sW4[(k4 * 4 + 3) * 16 + txl];
#pragma unroll
        for (int j = 0; j < 4; ++j) {
            float4 hq = sh4[ty * 4 + j][k4];
            acc[j][0] = fmaf(hq.x, w0.x, fmaf(hq.y, w1.x, fmaf(hq.z, w2.x, fmaf(hq.w, w3.x, acc[j][0]))));
            acc[j][1] = fmaf(hq.x, w0.y, fmaf(hq.y, w1.y, fmaf(hq.z, w2.y, fmaf(hq.w, w3.y, acc[j][1]))));
            acc[j][2] = fmaf(hq.x, w0.z, fmaf(hq.y, w1.z, fmaf(hq.z, w2.z, fmaf(hq.w, w3.z, acc[j][2]))));
            acc[j][3] = fmaf(hq.x, w0.w, fmaf(hq.y, w1.w, fmaf(hq.z, w2.w, fmaf(hq.w, w3.w, acc[j][3]))));
        }
    }

    // epilogue: relu(+b2) then partial 64->5 projection, reduce over txl lanes
    float pl[4][NC];
#pragma unroll
    for (int j = 0; j < 4; ++j)
#pragma unroll
        for (int c = 0; c < NC; ++c) pl[j][c] = 0.f;
#pragma unroll
    for (int j = 0; j < 4; ++j) {
#pragma unroll
        for (int i = 0; i < 4; ++i) {
            int f = txl * 4 + i;
            float h2 = fmaxf(acc[j][i] + sb2[f], 0.f);
#pragma unroll
            for (int c = 0; c < NC; ++c) pl[j][c] = fmaf(h2, swout[f][c], pl[j][c]);
        }
    }
#pragma unroll
    for (int o = 1; o < 16; o <<= 1) {
#pragma unroll
        for (int j = 0; j < 4; ++j)
#pragma unroll
            for (int c = 0; c < NC; ++c) pl[j][c] += __shfl_xor(pl[j][c], o, 64);
    }
    if (txl == 0) {
#pragma unroll
        for (int j = 0; j < 4; ++j) {
            int node = nb0 + ty * 4 + j;
            if (node < N) {
                float lg[NC];
#pragma unroll
                for (int c = 0; c < NC; ++c) lg[c] = pl[j][c] + sbout[c];
                float m = lg[0];
#pragma unroll
                for (int c = 1; c < NC; ++c) m = fmaxf(m, lg[c]);
                float ssum = 0.f, ex[NC];
#pragma unroll
                for (int c = 0; c < NC; ++c) { ex[c] = __expf(lg[c] - m); ssum += ex[c]; }
                float inv = 1.0f / ssum;
#pragma unroll
                for (int c = 0; c < NC; ++c) out[(size_t)node * NC + c] = ex[c] * inv;
            }
        }
    }
}

// ---------------- launch ----------------

extern "C" void kernel_launch(void* const* d_in, const int* in_sizes, int n_in,
                              void* d_out, int out_size, void* d_ws, size_t ws_size,
                              hipStream_t stream) {
    const float* x   = (const float*)d_in[0];
    const int*   ei  = (const int*)d_in[1];     // [2, E]: src = ei, dst = ei+E
    const float* W1  = (const float*)d_in[3];
    const float* b1  = (const float*)d_in[4];
    const float* W2  = (const float*)d_in[5];
    const float* b2  = (const float*)d_in[6];
    const float* Wo  = (const float*)d_in[7];
    const float* bo  = (const float*)d_in[8];
    float* out = (float*)d_out;

    const int N = in_sizes[2];          // batch array length = N_NODES (assumed <= 131072)
    const int E = in_sizes[1] / 2;

    // workspace partition (256B aligned)
    size_t off = 0;
    char* base = (char*)d_ws;
    auto alloc = [&](size_t bytes) -> void* {
        off = (off + 255) & ~(size_t)255;
        void* r = base + off;
        off += bytes;
        return r;
    };
    int*      bcount  = (int*)alloc((size_t)NBMAX * 4);
    int*      bbase   = (int*)alloc(((size_t)NBMAX + 1) * 4);
    int*      bcursor = (int*)alloc((size_t)NBMAX * 4);
    unsigned* pairbuf = (unsigned*)alloc((size_t)E * 4);
    int*      offsets = (int*)alloc(((size_t)N + 1) * 4);
    int*      csr_src = (int*)alloc((size_t)E * 4);
    float*    dinv    = (float*)alloc((size_t)N * 4);
    float*    aggH    = (float*)alloc((size_t)N * HID * 4);
    float*    g1      = (float*)alloc((size_t)N * HID * 4);

    const int T = 256;
    int gNF = ((N * HID) + T - 1) / T;    // one wave per node (4 waves/block)

    const int* src = ei;
    const int* dst = ei + E;

    int nb = (N + WINN - 1) >> WSH;                    // number of windows/buckets
    int chunk = (E + NBLK_FILL - 1) / NBLK_FILL;       // edges per fill block

    // bucketed CSR build
    k_zero_i32<<<(nb + 255) / 256, 256, 0, stream>>>(bcount, nb);
    k_bcount<<<NBLK_FILL, 256, 0, stream>>>(dst, E, chunk, nb, bcount);
    k_bscan2<<<1, 512, 0, stream>>>(bcount, nb, N, bbase, bcursor, offsets);
    k_bfill<<<NBLK_FILL, 256, 0, stream>>>(src, dst, E, chunk, nb, bcursor, pairbuf);
    k_csr<<<nb, WINN, 0, stream>>>(pairbuf, bbase, N, offsets, csr_src, dinv);

    // layer 1 fused: g1 = relu(gcn1(x)) * dinv
    k_agg1<<<gNF, T, 0, stream>>>(x, W1, offsets, csr_src, dinv, b1, g1, N);

    // layer 2 aggregation BEFORE matmul (linearity): aggH = dinv*(g1 + Σ g1[s])
    k_aggG<<<gNF, T, 0, stream>>>(g1, offsets, csr_src, dinv, aggH, N);

    // fused tail: relu(aggH@W2+b2) @ Wout + bout -> softmax -> out
    int nbF = (N + 63) / 64;
    k_fuse<<<nbF, 256, 0, stream>>>(aggH, W2, b2, Wo, bo, out, N);
}

// Round 7
// 264.967 us; speedup vs baseline: 3.6743x; 1.1271x over previous
//
#include <hip/hip_runtime.h>

#define HID 64
#define NF 5
#define NC 5

#define WSH 8                 // window shift: 256 nodes per window
#define WINN 256              // nodes per window (== blockDim of k_csr)
#define NBMAX 512             // max windows supported (N <= 131072)
#define SRCB 17               // bits for src in packed pair (N <= 131072)
#define NBLK_FILL 160         // blocks for bcount/bfill (big chunks -> long write runs)

__global__ void k_zero_i32(int* __restrict__ p, int n) {
    int i = blockIdx.x * blockDim.x + threadIdx.x;
    if (i < n) p[i] = 0;
}

// ---------------- bucketed CSR build ----------------

__global__ __launch_bounds__(256) void k_bcount(const int* __restrict__ dst, int E, int chunk,
                                                int nb, int* __restrict__ bcount) {
    __shared__ int cnt[NBMAX];
    for (int i = threadIdx.x; i < nb; i += 256) cnt[i] = 0;
    __syncthreads();
    int c0 = blockIdx.x * chunk;
    int c1 = c0 + chunk; if (c1 > E) c1 = E;
    for (int i = c0 + threadIdx.x; i < c1; i += 256)
        atomicAdd(&cnt[dst[i] >> WSH], 1);
    __syncthreads();
    for (int i = threadIdx.x; i < nb; i += 256) {
        int v = cnt[i];
        if (v) atomicAdd(&bcount[i], v);
    }
}

__global__ __launch_bounds__(512) void k_bscan2(const int* __restrict__ bcount, int nb, int N,
                                                int* __restrict__ bbase, int* __restrict__ bcursor,
                                                int* __restrict__ offsets) {
    __shared__ int s[512];
    int t = threadIdx.x;
    int v = (t < nb) ? bcount[t] : 0;
    s[t] = v;
    __syncthreads();
    for (int o = 1; o < 512; o <<= 1) {
        int u = (t >= o) ? s[t - o] : 0;
        __syncthreads();
        s[t] += u;
        __syncthreads();
    }
    if (t < nb) { bbase[t] = s[t] - v; bcursor[t] = s[t] - v; }
    if (t == nb - 1) { bbase[nb] = s[t]; offsets[N] = s[t]; }
}

__global__ __launch_bounds__(256) void k_bfill(const int* __restrict__ src,
                                               const int* __restrict__ dst, int E, int chunk,
                                               int nb, int* __restrict__ bcursor,
                                               unsigned int* __restrict__ pairbuf) {
    __shared__ int cnt[NBMAX];
    __shared__ int wcur[NBMAX];
    for (int i = threadIdx.x; i < nb; i += 256) cnt[i] = 0;
    __syncthreads();
    int c0 = blockIdx.x * chunk;
    int c1 = c0 + chunk; if (c1 > E) c1 = E;
    for (int i = c0 + threadIdx.x; i < c1; i += 256)
        atomicAdd(&cnt[dst[i] >> WSH], 1);
    __syncthreads();
    for (int i = threadIdx.x; i < nb; i += 256) {
        int v = cnt[i];
        wcur[i] = v ? atomicAdd(&bcursor[i], v) : 0;
    }
    __syncthreads();
    for (int i = c0 + threadIdx.x; i < c1; i += 256) {
        int d = dst[i];
        int b = d >> WSH;
        int p = atomicAdd(&wcur[b], 1);
        pairbuf[p] = ((unsigned)(d & (WINN - 1)) << SRCB) | (unsigned)src[i];
    }
}

// Pass 4: one block per window. Also emits xs[n] = x[n,3,:]*dinv[n] (5-dim scaled
// feature table for layer-1 pre-matmul aggregation).
__global__ __launch_bounds__(WINN) void k_csr(const unsigned int* __restrict__ pairbuf,
                                              const int* __restrict__ bbase, int N,
                                              const float* __restrict__ x,
                                              int* __restrict__ offsets,
                                              int* __restrict__ csr_src,
                                              float* __restrict__ dinv,
                                              float* __restrict__ xs) {
    int b = blockIdx.x, t = threadIdx.x;
    int winStart = b << WSH;
    int rbeg = bbase[b], rend = bbase[b + 1];
    __shared__ int deg[WINN];
    __shared__ int cur[WINN];
    __shared__ int s[WINN];
    deg[t] = 0;
    __syncthreads();
    for (int p = rbeg + t; p < rend; p += WINN)
        atomicAdd(&deg[pairbuf[p] >> SRCB], 1);
    __syncthreads();
    int v = deg[t];
    s[t] = v;
    __syncthreads();
    for (int o = 1; o < WINN; o <<= 1) {
        int u = (t >= o) ? s[t - o] : 0;
        __syncthreads();
        s[t] += u;
        __syncthreads();
    }
    int node = winStart + t;
    if (node < N) {
        int base = rbeg + s[t] - v;
        offsets[node] = base;
        cur[t] = base;
        float dv = rsqrtf((float)v + 1.0f);
        dinv[node] = dv;
        const float* xr = x + (size_t)node * (4 * NF) + 3 * NF;
#pragma unroll
        for (int k = 0; k < NF; ++k) xs[(size_t)node * NF + k] = xr[k] * dv;
    }
    __syncthreads();
    for (int p = rbeg + t; p < rend; p += WINN) {
        unsigned u = pairbuf[p];
        int dl = u >> SRCB;
        int sn = u & ((1u << SRCB) - 1);
        int pos = atomicAdd(&cur[dl], 1);
        csr_src[pos] = sn;
    }
}

// ---------------- GCN layers ----------------

// Layer-1, aggregation in 5-dim input space (linearity of @W1):
// g1[d] = relu( dinv[d]*(xs[d] + Σ_s xs[s]) @ W1 + b1 ) * dinv[d]
// Wave: 8 edge groups (g=lane>>3) x 8 lanes; lane f=lane&7 (<5 active) loads xs[s][f].
__global__ __launch_bounds__(256) void k_aggX(const float* __restrict__ xs,
                                              const float* __restrict__ W1,
                                              const int* __restrict__ offsets,
                                              const int* __restrict__ csr_src,
                                              const float* __restrict__ dinv,
                                              const float* __restrict__ b1,
                                              float* __restrict__ g1, int N) {
    int wid = (blockIdx.x * blockDim.x + threadIdx.x) >> 6;
    int lane = threadIdx.x & 63;
    int g = lane >> 3;
    int f = lane & 7;
    // W1 column for this lane's output feature (5 regs, coalesced across lanes)
    float w0 = W1[0 * HID + lane], w1 = W1[1 * HID + lane], w2 = W1[2 * HID + lane],
          w3 = W1[3 * HID + lane], w4 = W1[4 * HID + lane];
    if (wid >= N) return;
    int e0 = offsets[wid], e1 = offsets[wid + 1];
    bool fa = (f < NF);
    float acc = 0.f;
    int ee = e0 + g;
    int s = (ee < e1) ? csr_src[ee] : -1;
    for (int e = e0; e < e1; e += 8) {
        int cs = s;
        int en = e + 8 + g;
        s = (en < e1) ? csr_src[en] : -1;       // prefetch next iter's index
        if (cs >= 0 && fa) acc += xs[(size_t)cs * NF + f];
    }
    if (g == 0 && fa) acc += xs[(size_t)wid * NF + f];   // self term (once)
    // sum the 8 edge groups: partners at xor 8/16/32 share the same f
    acc += __shfl_xor(acc, 8, 64);
    acc += __shfl_xor(acc, 16, 64);
    acc += __shfl_xor(acc, 32, 64);
    // broadcast aggregated features 0..4 within each 8-lane group
    float a0 = __shfl(acc, 0, 8), a1 = __shfl(acc, 1, 8), a2 = __shfl(acc, 2, 8),
          a3 = __shfl(acc, 3, 8), a4 = __shfl(acc, 4, 8);
    float dv = dinv[wid];
    float sres = a0 * w0 + a1 * w1 + a2 * w2 + a3 * w3 + a4 * w4;
    float r = fmaxf(fmaf(dv, sres, b1[lane]), 0.f) * dv;  // g1 = relu(.)*dinv
    g1[(size_t)wid * HID + lane] = r;
}

// Layer-2 pre-matmul aggregate: aggH[d] = dinv[d]*( g1[d] + Σ_s g1[s] )
__global__ __launch_bounds__(256) void k_aggG(const float* __restrict__ g1,
                                              const int* __restrict__ offsets,
                                              const int* __restrict__ csr_src,
                                              const float* __restrict__ dinv,
                                              float* __restrict__ aggH, int N) {
    int wid = (blockIdx.x * blockDim.x + threadIdx.x) >> 6;
    if (wid >= N) return;
    int lane = threadIdx.x & 63;
    int g = lane >> 4;
    int fq = (lane & 15) << 2;
    int e0 = offsets[wid], e1 = offsets[wid + 1];
    float4 acc = {0.f, 0.f, 0.f, 0.f};
    int ee = e0 + g;
    int s = (ee < e1) ? csr_src[ee] : -1;
    for (int e = e0; e < e1; e += 4) {
        int cs = s;
        int en = e + 4 + g;
        s = (en < e1) ? csr_src[en] : -1;       // prefetch next iter's index
        if (cs >= 0) {
            float4 v = *reinterpret_cast<const float4*>(g1 + (size_t)cs * HID + fq);
            acc.x += v.x; acc.y += v.y; acc.z += v.z; acc.w += v.w;
        }
    }
#pragma unroll
    for (int o = 16; o < 64; o <<= 1) {
        acc.x += __shfl_xor(acc.x, o, 64);
        acc.y += __shfl_xor(acc.y, o, 64);
        acc.z += __shfl_xor(acc.z, o, 64);
        acc.w += __shfl_xor(acc.w, o, 64);
    }
    if (lane < 16) {
        float4 self = *reinterpret_cast<const float4*>(g1 + (size_t)wid * HID + fq);
        float dv = dinv[wid];
        float4 r;
        r.x = dv * (acc.x + self.x);
        r.y = dv * (acc.y + self.y);
        r.z = dv * (acc.z + self.z);
        r.w = dv * (acc.w + self.w);
        *reinterpret_cast<float4*>(aggH + (size_t)wid * HID + fq) = r;
    }
}

// Fused tail: H2 = relu(aggH @ W2 + b2); out = softmax(H2 @ Wout + bout).
__global__ __launch_bounds__(256) void k_fuse(const float* __restrict__ aggH,
                                              const float* __restrict__ W2,
                                              const float* __restrict__ b2,
                                              const float* __restrict__ Wout,
                                              const float* __restrict__ bout,
                                              float* __restrict__ out, int N) {
    __shared__ float4 sh4[64][17];      // aggH tile, padded (bank-spread)
    __shared__ float4 sW4[64 * 16];     // W2 row-major float4 quads
    __shared__ float  swout[64][NC];
    __shared__ float  sb2[64];
    __shared__ float  sbout[8];
    int tx = threadIdx.x;
    int nb0 = blockIdx.x * 64;

    const float4* W2_4 = reinterpret_cast<const float4*>(W2);
    for (int i = tx; i < 64 * 16; i += 256) sW4[i] = W2_4[i];
    const float4* aggH4 = reinterpret_cast<const float4*>(aggH);
    for (int i = tx; i < 64 * 16; i += 256) {
        int row = i >> 4, c4 = i & 15;
        int node = nb0 + row;
        float4 v = {0.f, 0.f, 0.f, 0.f};
        if (node < N) v = aggH4[(size_t)node * 16 + c4];
        sh4[row][c4] = v;
    }
    if (tx < 64) sb2[tx] = b2[tx];
    for (int i = tx; i < 64 * NC; i += 256) swout[i / NC][i % NC] = Wout[i];
    if (tx < NC) sbout[tx] = bout[tx];
    __syncthreads();

    int ty = tx >> 4;       // local node group: rows ty*4 .. ty*4+3
    int txl = tx & 15;      // feature quad: f = txl*4 .. txl*4+3

    float acc[4][4];
#pragma unroll
    for (int j = 0; j < 4; ++j)
#pragma unroll
        for (int i = 0; i < 4; ++i) acc[j][i] = 0.f;

    for (int k4 = 0; k4 < 16; ++k4) {
        float4 w0 = sW4[(k4 * 4 + 0) * 16 + txl];
        float4 w1 = sW4[(k4 * 4 + 1) * 16 + txl];
        float4 w2 = sW4[(k4 * 4 + 2) * 16 + txl];
        float4 w3 = sW4[(k4 * 4 + 3) * 16 + txl];
#pragma unroll
        for (int j = 0; j < 4; ++j) {
            float4 hq = sh4[ty * 4 + j][k4];
            acc[j][0] = fmaf(hq.x, w0.x, fmaf(hq.y, w1.x, fmaf(hq.z, w2.x, fmaf(hq.w, w3.x, acc[j][0]))));
            acc[j][1] = fmaf(hq.x, w0.y, fmaf(hq.y, w1.y, fmaf(hq.z, w2.y, fmaf(hq.w, w3.y, acc[j][1]))));
            acc[j][2] = fmaf(hq.x, w0.z, fmaf(hq.y, w1.z, fmaf(hq.z, w2.z, fmaf(hq.w, w3.z, acc[j][2]))));
            acc[j][3] = fmaf(hq.x, w0.w, fmaf(hq.y, w1.w, fmaf(hq.z, w2.w, fmaf(hq.w, w3.w, acc[j][3]))));
        }
    }

    float pl[4][NC];
#pragma unroll
    for (int j = 0; j < 4; ++j)
#pragma unroll
        for (int c = 0; c < NC; ++c) pl[j][c] = 0.f;
#pragma unroll
    for (int j = 0; j < 4; ++j) {
#pragma unroll
        for (int i = 0; i < 4; ++i) {
            int f = txl * 4 + i;
            float h2 = fmaxf(acc[j][i] + sb2[f], 0.f);
#pragma unroll
            for (int c = 0; c < NC; ++c) pl[j][c] = fmaf(h2, swout[f][c], pl[j][c]);
        }
    }
#pragma unroll
    for (int o = 1; o < 16; o <<= 1) {
#pragma unroll
        for (int j = 0; j < 4; ++j)
#pragma unroll
            for (int c = 0; c < NC; ++c) pl[j][c] += __shfl_xor(pl[j][c], o, 64);
    }
    if (txl == 0) {
#pragma unroll
        for (int j = 0; j < 4; ++j) {
            int node = nb0 + ty * 4 + j;
            if (node < N) {
                float lg[NC];
#pragma unroll
                for (int c = 0; c < NC; ++c) lg[c] = pl[j][c] + sbout[c];
                float m = lg[0];
#pragma unroll
                for (int c = 1; c < NC; ++c) m = fmaxf(m, lg[c]);
                float ssum = 0.f, ex[NC];
#pragma unroll
                for (int c = 0; c < NC; ++c) { ex[c] = __expf(lg[c] - m); ssum += ex[c]; }
                float inv = 1.0f / ssum;
#pragma unroll
                for (int c = 0; c < NC; ++c) out[(size_t)node * NC + c] = ex[c] * inv;
            }
        }
    }
}

// ---------------- launch ----------------

extern "C" void kernel_launch(void* const* d_in, const int* in_sizes, int n_in,
                              void* d_out, int out_size, void* d_ws, size_t ws_size,
                              hipStream_t stream) {
    const float* x   = (const float*)d_in[0];
    const int*   ei  = (const int*)d_in[1];     // [2, E]: src = ei, dst = ei+E
    const float* W1  = (const float*)d_in[3];
    const float* b1  = (const float*)d_in[4];
    const float* W2  = (const float*)d_in[5];
    const float* b2  = (const float*)d_in[6];
    const float* Wo  = (const float*)d_in[7];
    const float* bo  = (const float*)d_in[8];
    float* out = (float*)d_out;

    const int N = in_sizes[2];          // batch array length = N_NODES (assumed <= 131072)
    const int E = in_sizes[1] / 2;

    // workspace partition (256B aligned)
    size_t off = 0;
    char* base = (char*)d_ws;
    auto alloc = [&](size_t bytes) -> void* {
        off = (off + 255) & ~(size_t)255;
        void* r = base + off;
        off += bytes;
        return r;
    };
    int*      bcount  = (int*)alloc((size_t)NBMAX * 4);
    int*      bbase   = (int*)alloc(((size_t)NBMAX + 1) * 4);
    int*      bcursor = (int*)alloc((size_t)NBMAX * 4);
    unsigned* pairbuf = (unsigned*)alloc((size_t)E * 4);
    int*      offsets = (int*)alloc(((size_t)N + 1) * 4);
    int*      csr_src = (int*)alloc((size_t)E * 4);
    float*    dinv    = (float*)alloc((size_t)N * 4);
    float*    xs      = (float*)alloc((size_t)N * NF * 4);
    float*    g1      = (float*)alloc((size_t)N * HID * 4);
    float*    aggH    = (float*)alloc((size_t)N * HID * 4);

    const int T = 256;
    int gNF = ((N * HID) + T - 1) / T;    // one wave per node (4 waves/block)

    const int* src = ei;
    const int* dst = ei + E;

    int nb = (N + WINN - 1) >> WSH;                    // number of windows/buckets
    int chunk = (E + NBLK_FILL - 1) / NBLK_FILL;       // edges per fill block

    // bucketed CSR build (+ xs table)
    k_zero_i32<<<(nb + 255) / 256, 256, 0, stream>>>(bcount, nb);
    k_bcount<<<NBLK_FILL, 256, 0, stream>>>(dst, E, chunk, nb, bcount);
    k_bscan2<<<1, 512, 0, stream>>>(bcount, nb, N, bbase, bcursor, offsets);
    k_bfill<<<NBLK_FILL, 256, 0, stream>>>(src, dst, E, chunk, nb, bcursor, pairbuf);
    k_csr<<<nb, WINN, 0, stream>>>(pairbuf, bbase, N, x, offsets, csr_src, dinv, xs);

    // layer 1: aggregate xs in 5-dim, then @W1 per node: g1 = relu(.)*dinv
    k_aggX<<<gNF, T, 0, stream>>>(xs, W1, offsets, csr_src, dinv, b1, g1, N);

    // layer 2 aggregation BEFORE matmul: aggH = dinv*(g1 + Σ g1[s])
    k_aggG<<<gNF, T, 0, stream>>>(g1, offsets, csr_src, dinv, aggH, N);

    // fused tail: relu(aggH@W2+b2) @ Wout + bout -> softmax -> out
    int nbF = (N + 63) / 64;
    k_fuse<<<nbF, 256, 0, stream>>>(aggH, W2, b2, Wo, bo, out, N);
}

// Round 8
// 244.579 us; speedup vs baseline: 3.9806x; 1.0834x over previous
//
#include <hip/hip_runtime.h>
#include <hip/hip_fp16.h>

#define HID 64
#define NF 5
#define NC 5

#define WSH 8                 // window shift: 256 nodes per window
#define WINN 256              // nodes per window (== blockDim of k_csr)
#define NBMAX 512             // max windows supported (N <= 131072)
#define SRCB 17               // bits for src in packed pair (N <= 131072)
#define NBLK_FILL 160         // blocks for bcount/bfill (big chunks -> long write runs)

__global__ void k_zero_i32(int* __restrict__ p, int n) {
    int i = blockIdx.x * blockDim.x + threadIdx.x;
    if (i < n) p[i] = 0;
}

// ---------------- bucketed CSR build ----------------

__global__ __launch_bounds__(256) void k_bcount(const int* __restrict__ dst, int E, int chunk,
                                                int nb, int* __restrict__ bcount) {
    __shared__ int cnt[NBMAX];
    for (int i = threadIdx.x; i < nb; i += 256) cnt[i] = 0;
    __syncthreads();
    int c0 = blockIdx.x * chunk;
    int c1 = c0 + chunk; if (c1 > E) c1 = E;
    for (int i = c0 + threadIdx.x; i < c1; i += 256)
        atomicAdd(&cnt[dst[i] >> WSH], 1);
    __syncthreads();
    for (int i = threadIdx.x; i < nb; i += 256) {
        int v = cnt[i];
        if (v) atomicAdd(&bcount[i], v);
    }
}

__global__ __launch_bounds__(512) void k_bscan2(const int* __restrict__ bcount, int nb, int N,
                                                int* __restrict__ bbase, int* __restrict__ bcursor,
                                                int* __restrict__ offsets) {
    __shared__ int s[512];
    int t = threadIdx.x;
    int v = (t < nb) ? bcount[t] : 0;
    s[t] = v;
    __syncthreads();
    for (int o = 1; o < 512; o <<= 1) {
        int u = (t >= o) ? s[t - o] : 0;
        __syncthreads();
        s[t] += u;
        __syncthreads();
    }
    if (t < nb) { bbase[t] = s[t] - v; bcursor[t] = s[t] - v; }
    if (t == nb - 1) { bbase[nb] = s[t]; offsets[N] = s[t]; }
}

__global__ __launch_bounds__(256) void k_bfill(const int* __restrict__ src,
                                               const int* __restrict__ dst, int E, int chunk,
                                               int nb, int* __restrict__ bcursor,
                                               unsigned int* __restrict__ pairbuf) {
    __shared__ int cnt[NBMAX];
    __shared__ int wcur[NBMAX];
    for (int i = threadIdx.x; i < nb; i += 256) cnt[i] = 0;
    __syncthreads();
    int c0 = blockIdx.x * chunk;
    int c1 = c0 + chunk; if (c1 > E) c1 = E;
    for (int i = c0 + threadIdx.x; i < c1; i += 256)
        atomicAdd(&cnt[dst[i] >> WSH], 1);
    __syncthreads();
    for (int i = threadIdx.x; i < nb; i += 256) {
        int v = cnt[i];
        wcur[i] = v ? atomicAdd(&bcursor[i], v) : 0;
    }
    __syncthreads();
    for (int i = c0 + threadIdx.x; i < c1; i += 256) {
        int d = dst[i];
        int b = d >> WSH;
        int p = atomicAdd(&wcur[b], 1);
        pairbuf[p] = ((unsigned)(d & (WINN - 1)) << SRCB) | (unsigned)src[i];
    }
}

// Pass 4: one block per window. Also emits xs[n] = x[n,3,:]*dinv[n].
__global__ __launch_bounds__(WINN) void k_csr(const unsigned int* __restrict__ pairbuf,
                                              const int* __restrict__ bbase, int N,
                                              const float* __restrict__ x,
                                              int* __restrict__ offsets,
                                              int* __restrict__ csr_src,
                                              float* __restrict__ dinv,
                                              float* __restrict__ xs) {
    int b = blockIdx.x, t = threadIdx.x;
    int winStart = b << WSH;
    int rbeg = bbase[b], rend = bbase[b + 1];
    __shared__ int deg[WINN];
    __shared__ int cur[WINN];
    __shared__ int s[WINN];
    deg[t] = 0;
    __syncthreads();
    for (int p = rbeg + t; p < rend; p += WINN)
        atomicAdd(&deg[pairbuf[p] >> SRCB], 1);
    __syncthreads();
    int v = deg[t];
    s[t] = v;
    __syncthreads();
    for (int o = 1; o < WINN; o <<= 1) {
        int u = (t >= o) ? s[t - o] : 0;
        __syncthreads();
        s[t] += u;
        __syncthreads();
    }
    int node = winStart + t;
    if (node < N) {
        int base = rbeg + s[t] - v;
        offsets[node] = base;
        cur[t] = base;
        float dv = rsqrtf((float)v + 1.0f);
        dinv[node] = dv;
        const float* xr = x + (size_t)node * (4 * NF) + 3 * NF;
#pragma unroll
        for (int k = 0; k < NF; ++k) xs[(size_t)node * NF + k] = xr[k] * dv;
    }
    __syncthreads();
    for (int p = rbeg + t; p < rend; p += WINN) {
        unsigned u = pairbuf[p];
        int dl = u >> SRCB;
        int sn = u & ((1u << SRCB) - 1);
        int pos = atomicAdd(&cur[dl], 1);
        csr_src[pos] = sn;
    }
}

// ---------------- GCN layers ----------------

// Layer-1, aggregation in 5-dim input space; g1 stored as fp16.
// g1[d] = relu( dinv[d]*(xs[d] + Σ_s xs[s]) @ W1 + b1 ) * dinv[d]
__global__ __launch_bounds__(256) void k_aggX(const float* __restrict__ xs,
                                              const float* __restrict__ W1,
                                              const int* __restrict__ offsets,
                                              const int* __restrict__ csr_src,
                                              const float* __restrict__ dinv,
                                              const float* __restrict__ b1,
                                              __half* __restrict__ g1, int N) {
    int wid = (blockIdx.x * blockDim.x + threadIdx.x) >> 6;
    int lane = threadIdx.x & 63;
    int g = lane >> 3;
    int f = lane & 7;
    // W1 column for this lane's output feature (5 regs, coalesced across lanes)
    float w0 = W1[0 * HID + lane], w1 = W1[1 * HID + lane], w2 = W1[2 * HID + lane],
          w3 = W1[3 * HID + lane], w4 = W1[4 * HID + lane];
    if (wid >= N) return;
    int e0 = offsets[wid], e1 = offsets[wid + 1];
    bool fa = (f < NF);
    float acc = 0.f;
    int ee = e0 + g;
    int s = (ee < e1) ? csr_src[ee] : -1;
    for (int e = e0; e < e1; e += 8) {
        int cs = s;
        int en = e + 8 + g;
        s = (en < e1) ? csr_src[en] : -1;       // prefetch next iter's index
        if (cs >= 0 && fa) acc += xs[(size_t)cs * NF + f];
    }
    if (g == 0 && fa) acc += xs[(size_t)wid * NF + f];   // self term (once)
    acc += __shfl_xor(acc, 8, 64);
    acc += __shfl_xor(acc, 16, 64);
    acc += __shfl_xor(acc, 32, 64);
    float a0 = __shfl(acc, 0, 8), a1 = __shfl(acc, 1, 8), a2 = __shfl(acc, 2, 8),
          a3 = __shfl(acc, 3, 8), a4 = __shfl(acc, 4, 8);
    float dv = dinv[wid];
    float sres = a0 * w0 + a1 * w1 + a2 * w2 + a3 * w3 + a4 * w4;
    float r = fmaxf(fmaf(dv, sres, b1[lane]), 0.f) * dv;  // g1 = relu(.)*dinv
    g1[(size_t)wid * HID + lane] = __float2half(r);
}

// Layer-2 pre-matmul aggregate over fp16 g1 rows (128 B each), 8 edges in flight:
// aggH[d] = dinv[d]*( g1[d] + Σ_s g1[s] ), fp32 accumulate/output.
__global__ __launch_bounds__(256) void k_aggG(const __half* __restrict__ g1,
                                              const int* __restrict__ offsets,
                                              const int* __restrict__ csr_src,
                                              const float* __restrict__ dinv,
                                              float* __restrict__ aggH, int N) {
    int wid = (blockIdx.x * blockDim.x + threadIdx.x) >> 6;
    if (wid >= N) return;
    int lane = threadIdx.x & 63;
    int g = lane >> 3;              // 8 edge groups
    int f8 = (lane & 7) << 3;       // 8 features per lane
    int e0 = offsets[wid], e1 = offsets[wid + 1];
    float acc[8];
#pragma unroll
    for (int i = 0; i < 8; ++i) acc[i] = 0.f;
    int ee = e0 + g;
    int s = (ee < e1) ? csr_src[ee] : -1;
    for (int e = e0; e < e1; e += 8) {
        int cs = s;
        int en = e + 8 + g;
        s = (en < e1) ? csr_src[en] : -1;       // prefetch next iter's index
        if (cs >= 0) {
            float4 raw = *reinterpret_cast<const float4*>(g1 + (size_t)cs * HID + f8);
            float2 p0 = __half22float2(*reinterpret_cast<__half2*>(&raw.x));
            float2 p1 = __half22float2(*reinterpret_cast<__half2*>(&raw.y));
            float2 p2 = __half22float2(*reinterpret_cast<__half2*>(&raw.z));
            float2 p3 = __half22float2(*reinterpret_cast<__half2*>(&raw.w));
            acc[0] += p0.x; acc[1] += p0.y; acc[2] += p1.x; acc[3] += p1.y;
            acc[4] += p2.x; acc[5] += p2.y; acc[6] += p3.x; acc[7] += p3.y;
        }
    }
#pragma unroll
    for (int o = 8; o < 64; o <<= 1) {
#pragma unroll
        for (int i = 0; i < 8; ++i) acc[i] += __shfl_xor(acc[i], o, 64);
    }
    if (lane < 8) {
        float4 raw = *reinterpret_cast<const float4*>(g1 + (size_t)wid * HID + f8);
        float2 p0 = __half22float2(*reinterpret_cast<__half2*>(&raw.x));
        float2 p1 = __half22float2(*reinterpret_cast<__half2*>(&raw.y));
        float2 p2 = __half22float2(*reinterpret_cast<__half2*>(&raw.z));
        float2 p3 = __half22float2(*reinterpret_cast<__half2*>(&raw.w));
        float dv = dinv[wid];
        float4 r0, r1;
        r0.x = dv * (acc[0] + p0.x); r0.y = dv * (acc[1] + p0.y);
        r0.z = dv * (acc[2] + p1.x); r0.w = dv * (acc[3] + p1.y);
        r1.x = dv * (acc[4] + p2.x); r1.y = dv * (acc[5] + p2.y);
        r1.z = dv * (acc[6] + p3.x); r1.w = dv * (acc[7] + p3.y);
        float4* dst4 = reinterpret_cast<float4*>(aggH + (size_t)wid * HID + f8);
        dst4[0] = r0;
        dst4[1] = r1;
    }
}

// Fused tail: H2 = relu(aggH @ W2 + b2); out = softmax(H2 @ Wout + bout).
__global__ __launch_bounds__(256) void k_fuse(const float* __restrict__ aggH,
                                              const float* __restrict__ W2,
                                              const float* __restrict__ b2,
                                              const float* __restrict__ Wout,
                                              const float* __restrict__ bout,
                                              float* __restrict__ out, int N) {
    __shared__ float4 sh4[64][17];      // aggH tile, padded (bank-spread)
    __shared__ float4 sW4[64 * 16];     // W2 row-major float4 quads
    __shared__ float  swout[64][NC];
    __shared__ float  sb2[64];
    __shared__ float  sbout[8];
    int tx = threadIdx.x;
    int nb0 = blockIdx.x * 64;

    const float4* W2_4 = reinterpret_cast<const float4*>(W2);
    for (int i = tx; i < 64 * 16; i += 256) sW4[i] = W2_4[i];
    const float4* aggH4 = reinterpret_cast<const float4*>(aggH);
    for (int i = tx; i < 64 * 16; i += 256) {
        int row = i >> 4, c4 = i & 15;
        int node = nb0 + row;
        float4 v = {0.f, 0.f, 0.f, 0.f};
        if (node < N) v = aggH4[(size_t)node * 16 + c4];
        sh4[row][c4] = v;
    }
    if (tx < 64) sb2[tx] = b2[tx];
    for (int i = tx; i < 64 * NC; i += 256) swout[i / NC][i % NC] = Wout[i];
    if (tx < NC) sbout[tx] = bout[tx];
    __syncthreads();

    int ty = tx >> 4;       // local node group: rows ty*4 .. ty*4+3
    int txl = tx & 15;      // feature quad: f = txl*4 .. txl*4+3

    float acc[4][4];
#pragma unroll
    for (int j = 0; j < 4; ++j)
#pragma unroll
        for (int i = 0; i < 4; ++i) acc[j][i] = 0.f;

    for (int k4 = 0; k4 < 16; ++k4) {
        float4 w0 = sW4[(k4 * 4 + 0) * 16 + txl];
        float4 w1 = sW4[(k4 * 4 + 1) * 16 + txl];
        float4 w2 = sW4[(k4 * 4 + 2) * 16 + txl];
        float4 w3 = sW4[(k4 * 4 + 3) * 16 + txl];
#pragma unroll
        for (int j = 0; j < 4; ++j) {
            float4 hq = sh4[ty * 4 + j][k4];
            acc[j][0] = fmaf(hq.x, w0.x, fmaf(hq.y, w1.x, fmaf(hq.z, w2.x, fmaf(hq.w, w3.x, acc[j][0]))));
            acc[j][1] = fmaf(hq.x, w0.y, fmaf(hq.y, w1.y, fmaf(hq.z, w2.y, fmaf(hq.w, w3.y, acc[j][1]))));
            acc[j][2] = fmaf(hq.x, w0.z, fmaf(hq.y, w1.z, fmaf(hq.z, w2.z, fmaf(hq.w, w3.z, acc[j][2]))));
            acc[j][3] = fmaf(hq.x, w0.w, fmaf(hq.y, w1.w, fmaf(hq.z, w2.w, fmaf(hq.w, w3.w, acc[j][3]))));
        }
    }

    float pl[4][NC];
#pragma unroll
    for (int j = 0; j < 4; ++j)
#pragma unroll
        for (int c = 0; c < NC; ++c) pl[j][c] = 0.f;
#pragma unroll
    for (int j = 0; j < 4; ++j) {
#pragma unroll
        for (int i = 0; i < 4; ++i) {
            int f = txl * 4 + i;
            float h2 = fmaxf(acc[j][i] + sb2[f], 0.f);
#pragma unroll
            for (int c = 0; c < NC; ++c) pl[j][c] = fmaf(h2, swout[f][c], pl[j][c]);
        }
    }
#pragma unroll
    for (int o = 1; o < 16; o <<= 1) {
#pragma unroll
        for (int j = 0; j < 4; ++j)
#pragma unroll
            for (int c = 0; c < NC; ++c) pl[j][c] += __shfl_xor(pl[j][c], o, 64);
    }
    if (txl == 0) {
#pragma unroll
        for (int j = 0; j < 4; ++j) {
            int node = nb0 + ty * 4 + j;
            if (node < N) {
                float lg[NC];
#pragma unroll
                for (int c = 0; c < NC; ++c) lg[c] = pl[j][c] + sbout[c];
                float m = lg[0];
#pragma unroll
                for (int c = 1; c < NC; ++c) m = fmaxf(m, lg[c]);
                float ssum = 0.f, ex[NC];
#pragma unroll
                for (int c = 0; c < NC; ++c) { ex[c] = __expf(lg[c] - m); ssum += ex[c]; }
                float inv = 1.0f / ssum;
#pragma unroll
                for (int c = 0; c < NC; ++c) out[(size_t)node * NC + c] = ex[c] * inv;
            }
        }
    }
}

// ---------------- launch ----------------

extern "C" void kernel_launch(void* const* d_in, const int* in_sizes, int n_in,
                              void* d_out, int out_size, void* d_ws, size_t ws_size,
                              hipStream_t stream) {
    const float* x   = (const float*)d_in[0];
    const int*   ei  = (const int*)d_in[1];     // [2, E]: src = ei, dst = ei+E
    const float* W1  = (const float*)d_in[3];
    const float* b1  = (const float*)d_in[4];
    const float* W2  = (const float*)d_in[5];
    const float* b2  = (const float*)d_in[6];
    const float* Wo  = (const float*)d_in[7];
    const float* bo  = (const float*)d_in[8];
    float* out = (float*)d_out;

    const int N = in_sizes[2];          // batch array length = N_NODES (assumed <= 131072)
    const int E = in_sizes[1] / 2;

    // workspace partition (256B aligned)
    size_t off = 0;
    char* base = (char*)d_ws;
    auto alloc = [&](size_t bytes) -> void* {
        off = (off + 255) & ~(size_t)255;
        void* r = base + off;
        off += bytes;
        return r;
    };
    int*      bcount  = (int*)alloc((size_t)NBMAX * 4);
    int*      bbase   = (int*)alloc(((size_t)NBMAX + 1) * 4);
    int*      bcursor = (int*)alloc((size_t)NBMAX * 4);
    unsigned* pairbuf = (unsigned*)alloc((size_t)E * 4);
    int*      offsets = (int*)alloc(((size_t)N + 1) * 4);
    int*      csr_src = (int*)alloc((size_t)E * 4);
    float*    dinv    = (float*)alloc((size_t)N * 4);
    float*    xs      = (float*)alloc((size_t)N * NF * 4);
    __half*   g1      = (__half*)alloc((size_t)N * HID * 2);
    float*    aggH    = (float*)alloc((size_t)N * HID * 4);

    const int T = 256;
    int gNF = ((N * HID) + T - 1) / T;    // one wave per node (4 waves/block)

    const int* src = ei;
    const int* dst = ei + E;

    int nb = (N + WINN - 1) >> WSH;                    // number of windows/buckets
    int chunk = (E + NBLK_FILL - 1) / NBLK_FILL;       // edges per fill block

    // bucketed CSR build (+ xs table)
    k_zero_i32<<<(nb + 255) / 256, 256, 0, stream>>>(bcount, nb);
    k_bcount<<<NBLK_FILL, 256, 0, stream>>>(dst, E, chunk, nb, bcount);
    k_bscan2<<<1, 512, 0, stream>>>(bcount, nb, N, bbase, bcursor, offsets);
    k_bfill<<<NBLK_FILL, 256, 0, stream>>>(src, dst, E, chunk, nb, bcursor, pairbuf);
    k_csr<<<nb, WINN, 0, stream>>>(pairbuf, bbase, N, x, offsets, csr_src, dinv, xs);

    // layer 1: aggregate xs in 5-dim, then @W1 per node: g1 = relu(.)*dinv (fp16)
    k_aggX<<<gNF, T, 0, stream>>>(xs, W1, offsets, csr_src, dinv, b1, g1, N);

    // layer 2 aggregation BEFORE matmul: aggH = dinv*(g1 + Σ g1[s])
    k_aggG<<<gNF, T, 0, stream>>>(g1, offsets, csr_src, dinv, aggH, N);

    // fused tail: relu(aggH@W2+b2) @ Wout + bout -> softmax -> out
    int nbF = (N + 63) / 64;
    k_fuse<<<nbF, 256, 0, stream>>>(aggH, W2, b2, Wo, bo, out, N);
}

// Round 9
// 218.937 us; speedup vs baseline: 4.4469x; 1.1171x over previous
//
#include <hip/hip_runtime.h>
#include <hip/hip_fp16.h>

#define HID 64
#define NF 5
#define NC 5

#define WSH 9                 // window shift: 512 nodes per window
#define WINN 512              // nodes per window (== blockDim of k_csr)
#define NBMAX 256             // max windows (N <= 131072)
#define SRCB 17               // bits for src in packed pair (N <= 131072); dstLocal 9 bits
#define NBLK 256              // blocks for bcount/bfill

// ---------------- bucketed CSR build ----------------

// Pass 1: per-(block,bucket) histogram -> cntmat[blk][bucket] (coalesced store).
__global__ __launch_bounds__(512) void k_bcount(const int* __restrict__ dst, int E, int chunk,
                                                int nb, int* __restrict__ cntmat) {
    __shared__ int cnt[NBMAX];
    int t = threadIdx.x;
    for (int i = t; i < nb; i += 512) cnt[i] = 0;
    __syncthreads();
    int c0 = blockIdx.x * chunk;
    int c1 = c0 + chunk; if (c1 > E) c1 = E;
    for (int i = c0 + t; i < c1; i += 512)
        atomicAdd(&cnt[dst[i] >> WSH], 1);
    __syncthreads();
    for (int i = t; i < nb; i += 512) cntmat[blockIdx.x * nb + i] = cnt[i];
}

// Pass 2a: per-bucket exclusive scan over the NBLK block counts (in place) + btot.
__global__ __launch_bounds__(NBLK) void k_wscan(int* __restrict__ cntmat, int nb,
                                                int* __restrict__ btot) {
    __shared__ int s[NBLK];
    int b = blockIdx.x;       // bucket
    int t = threadIdx.x;      // block index
    int v = cntmat[t * nb + b];
    s[t] = v;
    __syncthreads();
    for (int o = 1; o < NBLK; o <<= 1) {
        int u = (t >= o) ? s[t - o] : 0;
        __syncthreads();
        s[t] += u;
        __syncthreads();
    }
    cntmat[t * nb + b] = s[t] - v;            // exclusive prefix within bucket
    if (t == NBLK - 1) btot[b] = s[t];
}

// Pass 2b: exclusive scan of bucket totals -> bbase; offsets[N] = E.
__global__ __launch_bounds__(256) void k_bscan2(const int* __restrict__ btot, int nb, int N,
                                                int* __restrict__ bbase,
                                                int* __restrict__ offsets) {
    __shared__ int s[256];
    int t = threadIdx.x;
    int v = (t < nb) ? btot[t] : 0;
    s[t] = v;
    __syncthreads();
    for (int o = 1; o < 256; o <<= 1) {
        int u = (t >= o) ? s[t - o] : 0;
        __syncthreads();
        s[t] += u;
        __syncthreads();
    }
    if (t < nb) bbase[t] = s[t] - v;
    if (t == nb - 1) { bbase[nb] = s[t]; offsets[N] = s[t]; }
}

// Pass 3: scatter-only fill (bases precomputed; no recount, no claim atomics).
__global__ __launch_bounds__(512) void k_bfill(const int* __restrict__ src,
                                               const int* __restrict__ dst, int E, int chunk,
                                               int nb, const int* __restrict__ bbase,
                                               const int* __restrict__ cntmat,
                                               unsigned int* __restrict__ pairbuf) {
    __shared__ int wcur[NBMAX];
    int t = threadIdx.x;
    int blk = blockIdx.x;
    for (int i = t; i < nb; i += 512)
        wcur[i] = bbase[i] + cntmat[blk * nb + i];
    __syncthreads();
    int c0 = blk * chunk;
    int c1 = c0 + chunk; if (c1 > E) c1 = E;
    for (int i = c0 + t; i < c1; i += 512) {
        int d = dst[i];
        int b = d >> WSH;
        int p = atomicAdd(&wcur[b], 1);
        pairbuf[p] = ((unsigned)(d & (WINN - 1)) << SRCB) | (unsigned)src[i];
    }
}

// Pass 4: one block per 512-node window. Exclusive ownership of pair/CSR region.
// Emits offsets, csr_src, dinv, and xs[n] = x[n,3,:]*dinv[n].
__global__ __launch_bounds__(WINN) void k_csr(const unsigned int* __restrict__ pairbuf,
                                              const int* __restrict__ bbase, int N,
                                              const float* __restrict__ x,
                                              int* __restrict__ offsets,
                                              int* __restrict__ csr_src,
                                              float* __restrict__ dinv,
                                              float* __restrict__ xs) {
    int b = blockIdx.x, t = threadIdx.x;
    int winStart = b << WSH;
    int rbeg = bbase[b], rend = bbase[b + 1];
    __shared__ int deg[WINN];
    __shared__ int cur[WINN];
    __shared__ int s[WINN];
    deg[t] = 0;
    __syncthreads();
    for (int p = rbeg + t; p < rend; p += WINN)
        atomicAdd(&deg[pairbuf[p] >> SRCB], 1);
    __syncthreads();
    int v = deg[t];
    s[t] = v;
    __syncthreads();
    for (int o = 1; o < WINN; o <<= 1) {
        int u = (t >= o) ? s[t - o] : 0;
        __syncthreads();
        s[t] += u;
        __syncthreads();
    }
    int node = winStart + t;
    if (node < N) {
        int base = rbeg + s[t] - v;
        offsets[node] = base;
        cur[t] = base;
        float dv = rsqrtf((float)v + 1.0f);
        dinv[node] = dv;
        const float* xr = x + (size_t)node * (4 * NF) + 3 * NF;
#pragma unroll
        for (int k = 0; k < NF; ++k) xs[(size_t)node * NF + k] = xr[k] * dv;
    }
    __syncthreads();
    for (int p = rbeg + t; p < rend; p += WINN) {
        unsigned u = pairbuf[p];
        int dl = u >> SRCB;
        int sn = u & ((1u << SRCB) - 1);
        int pos = atomicAdd(&cur[dl], 1);
        csr_src[pos] = sn;
    }
}

// ---------------- GCN layers ----------------

// Layer-1, aggregation in 5-dim input space; g1 stored as fp16.
// g1[d] = relu( dinv[d]*(xs[d] + Σ_s xs[s]) @ W1 + b1 ) * dinv[d]
__global__ __launch_bounds__(256) void k_aggX(const float* __restrict__ xs,
                                              const float* __restrict__ W1,
                                              const int* __restrict__ offsets,
                                              const int* __restrict__ csr_src,
                                              const float* __restrict__ dinv,
                                              const float* __restrict__ b1,
                                              __half* __restrict__ g1, int N) {
    int wid = (blockIdx.x * blockDim.x + threadIdx.x) >> 6;
    int lane = threadIdx.x & 63;
    int g = lane >> 3;
    int f = lane & 7;
    // W1 column for this lane's output feature (5 regs, coalesced across lanes)
    float w0 = W1[0 * HID + lane], w1 = W1[1 * HID + lane], w2 = W1[2 * HID + lane],
          w3 = W1[3 * HID + lane], w4 = W1[4 * HID + lane];
    if (wid >= N) return;
    int e0 = offsets[wid], e1 = offsets[wid + 1];
    bool fa = (f < NF);
    float acc = 0.f;
    int ee = e0 + g;
    int s = (ee < e1) ? csr_src[ee] : -1;
    for (int e = e0; e < e1; e += 8) {
        int cs = s;
        int en = e + 8 + g;
        s = (en < e1) ? csr_src[en] : -1;       // prefetch next iter's index
        if (cs >= 0 && fa) acc += xs[(size_t)cs * NF + f];
    }
    if (g == 0 && fa) acc += xs[(size_t)wid * NF + f];   // self term (once)
    acc += __shfl_xor(acc, 8, 64);
    acc += __shfl_xor(acc, 16, 64);
    acc += __shfl_xor(acc, 32, 64);
    float a0 = __shfl(acc, 0, 8), a1 = __shfl(acc, 1, 8), a2 = __shfl(acc, 2, 8),
          a3 = __shfl(acc, 3, 8), a4 = __shfl(acc, 4, 8);
    float dv = dinv[wid];
    float sres = a0 * w0 + a1 * w1 + a2 * w2 + a3 * w3 + a4 * w4;
    float r = fmaxf(fmaf(dv, sres, b1[lane]), 0.f) * dv;  // g1 = relu(.)*dinv
    g1[(size_t)wid * HID + lane] = __float2half(r);
}

// Layer-2 pre-matmul aggregate over fp16 g1 rows (128 B each), 8 edges in flight:
// aggH[d] = dinv[d]*( g1[d] + Σ_s g1[s] ), fp32 accumulate/output.
__global__ __launch_bounds__(256) void k_aggG(const __half* __restrict__ g1,
                                              const int* __restrict__ offsets,
                                              const int* __restrict__ csr_src,
                                              const float* __restrict__ dinv,
                                              float* __restrict__ aggH, int N) {
    int wid = (blockIdx.x * blockDim.x + threadIdx.x) >> 6;
    if (wid >= N) return;
    int lane = threadIdx.x & 63;
    int g = lane >> 3;              // 8 edge groups
    int f8 = (lane & 7) << 3;       // 8 features per lane
    int e0 = offsets[wid], e1 = offsets[wid + 1];
    float acc[8];
#pragma unroll
    for (int i = 0; i < 8; ++i) acc[i] = 0.f;
    int ee = e0 + g;
    int s = (ee < e1) ? csr_src[ee] : -1;
    for (int e = e0; e < e1; e += 8) {
        int cs = s;
        int en = e + 8 + g;
        s = (en < e1) ? csr_src[en] : -1;       // prefetch next iter's index
        if (cs >= 0) {
            float4 raw = *reinterpret_cast<const float4*>(g1 + (size_t)cs * HID + f8);
            float2 p0 = __half22float2(*reinterpret_cast<__half2*>(&raw.x));
            float2 p1 = __half22float2(*reinterpret_cast<__half2*>(&raw.y));
            float2 p2 = __half22float2(*reinterpret_cast<__half2*>(&raw.z));
            float2 p3 = __half22float2(*reinterpret_cast<__half2*>(&raw.w));
            acc[0] += p0.x; acc[1] += p0.y; acc[2] += p1.x; acc[3] += p1.y;
            acc[4] += p2.x; acc[5] += p2.y; acc[6] += p3.x; acc[7] += p3.y;
        }
    }
#pragma unroll
    for (int o = 8; o < 64; o <<= 1) {
#pragma unroll
        for (int i = 0; i < 8; ++i) acc[i] += __shfl_xor(acc[i], o, 64);
    }
    if (lane < 8) {
        float4 raw = *reinterpret_cast<const float4*>(g1 + (size_t)wid * HID + f8);
        float2 p0 = __half22float2(*reinterpret_cast<__half2*>(&raw.x));
        float2 p1 = __half22float2(*reinterpret_cast<__half2*>(&raw.y));
        float2 p2 = __half22float2(*reinterpret_cast<__half2*>(&raw.z));
        float2 p3 = __half22float2(*reinterpret_cast<__half2*>(&raw.w));
        float dv = dinv[wid];
        float4 r0, r1;
        r0.x = dv * (acc[0] + p0.x); r0.y = dv * (acc[1] + p0.y);
        r0.z = dv * (acc[2] + p1.x); r0.w = dv * (acc[3] + p1.y);
        r1.x = dv * (acc[4] + p2.x); r1.y = dv * (acc[5] + p2.y);
        r1.z = dv * (acc[6] + p3.x); r1.w = dv * (acc[7] + p3.y);
        float4* dst4 = reinterpret_cast<float4*>(aggH + (size_t)wid * HID + f8);
        dst4[0] = r0;
        dst4[1] = r1;
    }
}

// Fused tail: H2 = relu(aggH @ W2 + b2); out = softmax(H2 @ Wout + bout).
__global__ __launch_bounds__(256) void k_fuse(const float* __restrict__ aggH,
                                              const float* __restrict__ W2,
                                              const float* __restrict__ b2,
                                              const float* __restrict__ Wout,
                                              const float* __restrict__ bout,
                                              float* __restrict__ out, int N) {
    __shared__ float4 sh4[64][17];      // aggH tile, padded (bank-spread)
    __shared__ float4 sW4[64 * 16];     // W2 row-major float4 quads
    __shared__ float  swout[64][NC];
    __shared__ float  sb2[64];
    __shared__ float  sbout[8];
    int tx = threadIdx.x;
    int nb0 = blockIdx.x * 64;

    const float4* W2_4 = reinterpret_cast<const float4*>(W2);
    for (int i = tx; i < 64 * 16; i += 256) sW4[i] = W2_4[i];
    const float4* aggH4 = reinterpret_cast<const float4*>(aggH);
    for (int i = tx; i < 64 * 16; i += 256) {
        int row = i >> 4, c4 = i & 15;
        int node = nb0 + row;
        float4 v = {0.f, 0.f, 0.f, 0.f};
        if (node < N) v = aggH4[(size_t)node * 16 + c4];
        sh4[row][c4] = v;
    }
    if (tx < 64) sb2[tx] = b2[tx];
    for (int i = tx; i < 64 * NC; i += 256) swout[i / NC][i % NC] = Wout[i];
    if (tx < NC) sbout[tx] = bout[tx];
    __syncthreads();

    int ty = tx >> 4;       // local node group: rows ty*4 .. ty*4+3
    int txl = tx & 15;      // feature quad: f = txl*4 .. txl*4+3

    float acc[4][4];
#pragma unroll
    for (int j = 0; j < 4; ++j)
#pragma unroll
        for (int i = 0; i < 4; ++i) acc[j][i] = 0.f;

    for (int k4 = 0; k4 < 16; ++k4) {
        float4 w0 = sW4[(k4 * 4 + 0) * 16 + txl];
        float4 w1 = sW4[(k4 * 4 + 1) * 16 + txl];
        float4 w2 = sW4[(k4 * 4 + 2) * 16 + txl];
        float4 w3 = sW4[(k4 * 4 + 3) * 16 + txl];
#pragma unroll
        for (int j = 0; j < 4; ++j) {
            float4 hq = sh4[ty * 4 + j][k4];
            acc[j][0] = fmaf(hq.x, w0.x, fmaf(hq.y, w1.x, fmaf(hq.z, w2.x, fmaf(hq.w, w3.x, acc[j][0]))));
            acc[j][1] = fmaf(hq.x, w0.y, fmaf(hq.y, w1.y, fmaf(hq.z, w2.y, fmaf(hq.w, w3.y, acc[j][1]))));
            acc[j][2] = fmaf(hq.x, w0.z, fmaf(hq.y, w1.z, fmaf(hq.z, w2.z, fmaf(hq.w, w3.z, acc[j][2]))));
            acc[j][3] = fmaf(hq.x, w0.w, fmaf(hq.y, w1.w, fmaf(hq.z, w2.w, fmaf(hq.w, w3.w, acc[j][3]))));
        }
    }

    float pl[4][NC];
#pragma unroll
    for (int j = 0; j < 4; ++j)
#pragma unroll
        for (int c = 0; c < NC; ++c) pl[j][c] = 0.f;
#pragma unroll
    for (int j = 0; j < 4; ++j) {
#pragma unroll
        for (int i = 0; i < 4; ++i) {
            int f = txl * 4 + i;
            float h2 = fmaxf(acc[j][i] + sb2[f], 0.f);
#pragma unroll
            for (int c = 0; c < NC; ++c) pl[j][c] = fmaf(h2, swout[f][c], pl[j][c]);
        }
    }
#pragma unroll
    for (int o = 1; o < 16; o <<= 1) {
#pragma unroll
        for (int j = 0; j < 4; ++j)
#pragma unroll
            for (int c = 0; c < NC; ++c) pl[j][c] += __shfl_xor(pl[j][c], o, 64);
    }
    if (txl == 0) {
#pragma unroll
        for (int j = 0; j < 4; ++j) {
            int node = nb0 + ty * 4 + j;
            if (node < N) {
                float lg[NC];
#pragma unroll
                for (int c = 0; c < NC; ++c) lg[c] = pl[j][c] + sbout[c];
                float m = lg[0];
#pragma unroll
                for (int c = 1; c < NC; ++c) m = fmaxf(m, lg[c]);
                float ssum = 0.f, ex[NC];
#pragma unroll
                for (int c = 0; c < NC; ++c) { ex[c] = __expf(lg[c] - m); ssum += ex[c]; }
                float inv = 1.0f / ssum;
#pragma unroll
                for (int c = 0; c < NC; ++c) out[(size_t)node * NC + c] = ex[c] * inv;
            }
        }
    }
}

// ---------------- launch ----------------

extern "C" void kernel_launch(void* const* d_in, const int* in_sizes, int n_in,
                              void* d_out, int out_size, void* d_ws, size_t ws_size,
                              hipStream_t stream) {
    const float* x   = (const float*)d_in[0];
    const int*   ei  = (const int*)d_in[1];     // [2, E]: src = ei, dst = ei+E
    const float* W1  = (const float*)d_in[3];
    const float* b1  = (const float*)d_in[4];
    const float* W2  = (const float*)d_in[5];
    const float* b2  = (const float*)d_in[6];
    const float* Wo  = (const float*)d_in[7];
    const float* bo  = (const float*)d_in[8];
    float* out = (float*)d_out;

    const int N = in_sizes[2];          // batch array length = N_NODES (assumed <= 131072)
    const int E = in_sizes[1] / 2;

    // workspace partition (256B aligned)
    size_t off = 0;
    char* base = (char*)d_ws;
    auto alloc = [&](size_t bytes) -> void* {
        off = (off + 255) & ~(size_t)255;
        void* r = base + off;
        off += bytes;
        return r;
    };
    int*      cntmat  = (int*)alloc((size_t)NBLK * NBMAX * 4);
    int*      btot    = (int*)alloc((size_t)NBMAX * 4);
    int*      bbase   = (int*)alloc(((size_t)NBMAX + 1) * 4);
    unsigned* pairbuf = (unsigned*)alloc((size_t)E * 4);
    int*      offsets = (int*)alloc(((size_t)N + 1) * 4);
    int*      csr_src = (int*)alloc((size_t)E * 4);
    float*    dinv    = (float*)alloc((size_t)N * 4);
    float*    xs      = (float*)alloc((size_t)N * NF * 4);
    __half*   g1      = (__half*)alloc((size_t)N * HID * 2);
    float*    aggH    = (float*)alloc((size_t)N * HID * 4);

    const int T = 256;
    int gNF = ((N * HID) + T - 1) / T;    // one wave per node (4 waves/block)

    const int* src = ei;
    const int* dst = ei + E;

    int nb = (N + WINN - 1) >> WSH;                // number of windows/buckets (<= 256)
    int chunk = (E + NBLK - 1) / NBLK;             // edges per fill block

    // bucketed CSR build (+ xs table)
    k_bcount<<<NBLK, 512, 0, stream>>>(dst, E, chunk, nb, cntmat);
    k_wscan<<<nb, NBLK, 0, stream>>>(cntmat, nb, btot);
    k_bscan2<<<1, 256, 0, stream>>>(btot, nb, N, bbase, offsets);
    k_bfill<<<NBLK, 512, 0, stream>>>(src, dst, E, chunk, nb, bbase, cntmat, pairbuf);
    k_csr<<<nb, WINN, 0, stream>>>(pairbuf, bbase, N, x, offsets, csr_src, dinv, xs);

    // layer 1: aggregate xs in 5-dim, then @W1 per node: g1 = relu(.)*dinv (fp16)
    k_aggX<<<gNF, T, 0, stream>>>(xs, W1, offsets, csr_src, dinv, b1, g1, N);

    // layer 2 aggregation BEFORE matmul: aggH = dinv*(g1 + Σ g1[s])
    k_aggG<<<gNF, T, 0, stream>>>(g1, offsets, csr_src, dinv, aggH, N);

    // fused tail: relu(aggH@W2+b2) @ Wout + bout -> softmax -> out
    int nbF = (N + 63) / 64;
    k_fuse<<<nbF, 256, 0, stream>>>(aggH, W2, b2, Wo, bo, out, N);
}

// Round 10
// 209.471 us; speedup vs baseline: 4.6478x; 1.0452x over previous
//
#include <hip/hip_runtime.h>
#include <hip/hip_fp16.h>

#define HID 64
#define NF 5
#define NC 5

#define WSH 9                 // window shift: 512 nodes per window
#define WINN 512              // nodes per window (== blockDim of k_csr)
#define NBMAX 256             // max windows (N <= 131072)
#define SRCB 17               // bits for src in packed pair (N <= 131072); dstLocal 9 bits
#define NBLK 256              // blocks for bcount/bfill

// ---------------- bucketed CSR build ----------------

// Pass 1: per-(block,bucket) histogram -> cntmat[blk][bucket] (coalesced store).
__global__ __launch_bounds__(512) void k_bcount(const int* __restrict__ dst, int E, int chunk,
                                                int nb, int* __restrict__ cntmat) {
    __shared__ int cnt[NBMAX];
    int t = threadIdx.x;
    for (int i = t; i < nb; i += 512) cnt[i] = 0;
    __syncthreads();
    int c0 = blockIdx.x * chunk;
    int c1 = c0 + chunk; if (c1 > E) c1 = E;
    for (int i = c0 + t; i < c1; i += 512)
        atomicAdd(&cnt[dst[i] >> WSH], 1);
    __syncthreads();
    for (int i = t; i < nb; i += 512) cntmat[blockIdx.x * nb + i] = cnt[i];
}

// Pass 2a: per-bucket exclusive scan over the NBLK block counts (in place) + btot.
__global__ __launch_bounds__(NBLK) void k_wscan(int* __restrict__ cntmat, int nb,
                                                int* __restrict__ btot) {
    __shared__ int s[NBLK];
    int b = blockIdx.x;       // bucket
    int t = threadIdx.x;      // block index
    int v = cntmat[t * nb + b];
    s[t] = v;
    __syncthreads();
    for (int o = 1; o < NBLK; o <<= 1) {
        int u = (t >= o) ? s[t - o] : 0;
        __syncthreads();
        s[t] += u;
        __syncthreads();
    }
    cntmat[t * nb + b] = s[t] - v;            // exclusive prefix within bucket
    if (t == NBLK - 1) btot[b] = s[t];
}

// Pass 2b: exclusive scan of bucket totals -> bbase; offsets[N] = E.
__global__ __launch_bounds__(256) void k_bscan2(const int* __restrict__ btot, int nb, int N,
                                                int* __restrict__ bbase,
                                                int* __restrict__ offsets) {
    __shared__ int s[256];
    int t = threadIdx.x;
    int v = (t < nb) ? btot[t] : 0;
    s[t] = v;
    __syncthreads();
    for (int o = 1; o < 256; o <<= 1) {
        int u = (t >= o) ? s[t - o] : 0;
        __syncthreads();
        s[t] += u;
        __syncthreads();
    }
    if (t < nb) bbase[t] = s[t] - v;
    if (t == nb - 1) { bbase[nb] = s[t]; offsets[N] = s[t]; }
}

// Pass 3: scatter-only fill (bases precomputed; no recount, no claim atomics).
__global__ __launch_bounds__(512) void k_bfill(const int* __restrict__ src,
                                               const int* __restrict__ dst, int E, int chunk,
                                               int nb, const int* __restrict__ bbase,
                                               const int* __restrict__ cntmat,
                                               unsigned int* __restrict__ pairbuf) {
    __shared__ int wcur[NBMAX];
    int t = threadIdx.x;
    int blk = blockIdx.x;
    for (int i = t; i < nb; i += 512)
        wcur[i] = bbase[i] + cntmat[blk * nb + i];
    __syncthreads();
    int c0 = blk * chunk;
    int c1 = c0 + chunk; if (c1 > E) c1 = E;
    for (int i = c0 + t; i < c1; i += 512) {
        int d = dst[i];
        int b = d >> WSH;
        int p = atomicAdd(&wcur[b], 1);
        pairbuf[p] = ((unsigned)(d & (WINN - 1)) << SRCB) | (unsigned)src[i];
    }
}

// Pass 4: one block per 512-node window. Exclusive ownership of pair/CSR region.
// Emits offsets, csr_src, dinv, and xs8[n] = {x[n,3,:]*dinv[n], pad 0} (32 B rows).
__global__ __launch_bounds__(WINN) void k_csr(const unsigned int* __restrict__ pairbuf,
                                              const int* __restrict__ bbase, int N,
                                              const float* __restrict__ x,
                                              int* __restrict__ offsets,
                                              int* __restrict__ csr_src,
                                              float* __restrict__ dinv,
                                              float* __restrict__ xs8) {
    int b = blockIdx.x, t = threadIdx.x;
    int winStart = b << WSH;
    int rbeg = bbase[b], rend = bbase[b + 1];
    __shared__ int deg[WINN];
    __shared__ int cur[WINN];
    __shared__ int s[WINN];
    deg[t] = 0;
    __syncthreads();
    for (int p = rbeg + t; p < rend; p += WINN)
        atomicAdd(&deg[pairbuf[p] >> SRCB], 1);
    __syncthreads();
    int v = deg[t];
    s[t] = v;
    __syncthreads();
    for (int o = 1; o < WINN; o <<= 1) {
        int u = (t >= o) ? s[t - o] : 0;
        __syncthreads();
        s[t] += u;
        __syncthreads();
    }
    int node = winStart + t;
    if (node < N) {
        int base = rbeg + s[t] - v;
        offsets[node] = base;
        cur[t] = base;
        float dv = rsqrtf((float)v + 1.0f);
        dinv[node] = dv;
        const float* xr = x + (size_t)node * (4 * NF) + 3 * NF;
        float4 v0, v1;
        v0.x = xr[0] * dv; v0.y = xr[1] * dv; v0.z = xr[2] * dv; v0.w = xr[3] * dv;
        v1.x = xr[4] * dv; v1.y = 0.f; v1.z = 0.f; v1.w = 0.f;
        float4* xp = reinterpret_cast<float4*>(xs8 + (size_t)node * 8);
        xp[0] = v0;
        xp[1] = v1;
    }
    __syncthreads();
    for (int p = rbeg + t; p < rend; p += WINN) {
        unsigned u = pairbuf[p];
        int dl = u >> SRCB;
        int sn = u & ((1u << SRCB) - 1);
        int pos = atomicAdd(&cur[dl], 1);
        csr_src[pos] = sn;
    }
}

// ---------------- GCN layers ----------------

// Layer-1, aggregation in padded 8-float input space; g1 stored as fp16.
// g1[d] = relu( dinv[d]*(xs[d] + Σ_s xs[s]) @ W1 + b1 ) * dinv[d]
// Wave: 32 edge groups (g=lane>>1) x 2 lanes; lane h=lane&1 loads float4 half-row.
__global__ __launch_bounds__(256) void k_aggX(const float* __restrict__ xs8,
                                              const float* __restrict__ W1,
                                              const int* __restrict__ offsets,
                                              const int* __restrict__ csr_src,
                                              const float* __restrict__ dinv,
                                              const float* __restrict__ b1,
                                              __half* __restrict__ g1, int N) {
    int wid = (blockIdx.x * blockDim.x + threadIdx.x) >> 6;
    int lane = threadIdx.x & 63;
    int g = lane >> 1;              // 32 edge groups
    int h = lane & 1;               // half-row selector (features h*4..h*4+3)
    // W1 column for this lane's output feature (5 regs, coalesced across lanes)
    float w0 = W1[0 * HID + lane], w1 = W1[1 * HID + lane], w2 = W1[2 * HID + lane],
          w3 = W1[3 * HID + lane], w4 = W1[4 * HID + lane];
    if (wid >= N) return;
    int e0 = offsets[wid], e1 = offsets[wid + 1];
    float4 acc = {0.f, 0.f, 0.f, 0.f};
    int ee = e0 + g;
    int s = (ee < e1) ? csr_src[ee] : -1;
    for (int e = e0; e < e1; e += 32) {
        int cs = s;
        int en = e + 32 + g;
        s = (en < e1) ? csr_src[en] : -1;       // prefetch next iter's index
        bool p = (cs >= 0);
        int csc = p ? cs : 0;                   // clamp: load always (exec-unmasked)
        float4 v = *reinterpret_cast<const float4*>(xs8 + (size_t)csc * 8 + (h << 2));
        if (p) { acc.x += v.x; acc.y += v.y; acc.z += v.z; acc.w += v.w; }
    }
    if (g == 0) {                               // self term (lanes 0,1)
        float4 v = *reinterpret_cast<const float4*>(xs8 + (size_t)wid * 8 + (h << 2));
        acc.x += v.x; acc.y += v.y; acc.z += v.z; acc.w += v.w;
    }
    // reduce across the 32 edge groups (partners share h)
#pragma unroll
    for (int o = 2; o < 64; o <<= 1) {
        acc.x += __shfl_xor(acc.x, o, 64);
        acc.y += __shfl_xor(acc.y, o, 64);
        acc.z += __shfl_xor(acc.z, o, 64);
        acc.w += __shfl_xor(acc.w, o, 64);
    }
    // gather the 5 aggregated features from the two h-classes
    float a0 = __shfl(acc.x, 0, 2), a1 = __shfl(acc.y, 0, 2),
          a2 = __shfl(acc.z, 0, 2), a3 = __shfl(acc.w, 0, 2),
          a4 = __shfl(acc.x, 1, 2);
    float dv = dinv[wid];
    float sres = a0 * w0 + a1 * w1 + a2 * w2 + a3 * w3 + a4 * w4;
    float r = fmaxf(fmaf(dv, sres, b1[lane]), 0.f) * dv;  // g1 = relu(.)*dinv
    g1[(size_t)wid * HID + lane] = __float2half(r);
}

// Layer-2 pre-matmul aggregate over fp16 g1 rows (128 B each), unroll x2:
// 16 rows in flight per wave. aggH[d] = dinv[d]*( g1[d] + Σ_s g1[s] ), fp32 acc.
__global__ __launch_bounds__(256) void k_aggG(const __half* __restrict__ g1,
                                              const int* __restrict__ offsets,
                                              const int* __restrict__ csr_src,
                                              const float* __restrict__ dinv,
                                              float* __restrict__ aggH, int N) {
    int wid = (blockIdx.x * blockDim.x + threadIdx.x) >> 6;
    if (wid >= N) return;
    int lane = threadIdx.x & 63;
    int g = lane >> 3;              // 8 edge groups
    int f8 = (lane & 7) << 3;       // 8 features per lane
    int e0 = offsets[wid], e1 = offsets[wid + 1];
    float acc[8];
#pragma unroll
    for (int i = 0; i < 8; ++i) acc[i] = 0.f;
    int ee = e0 + g;
    int s0 = (ee < e1) ? csr_src[ee] : -1;
    int s1 = (ee + 8 < e1) ? csr_src[ee + 8] : -1;
    for (int e = e0; e < e1; e += 16) {
        int cs0 = s0, cs1 = s1;
        int en0 = e + 16 + g, en1 = e + 24 + g;
        s0 = (en0 < e1) ? csr_src[en0] : -1;    // prefetch next iter's indices
        s1 = (en1 < e1) ? csr_src[en1] : -1;
        bool p0 = (cs0 >= 0), p1 = (cs1 >= 0);
        int c0 = p0 ? cs0 : 0, c1 = p1 ? cs1 : 0;   // clamp: loads exec-unmasked
        float4 raw0 = *reinterpret_cast<const float4*>(g1 + (size_t)c0 * HID + f8);
        float4 raw1 = *reinterpret_cast<const float4*>(g1 + (size_t)c1 * HID + f8);
        if (p0) {
            float2 q0 = __half22float2(*reinterpret_cast<__half2*>(&raw0.x));
            float2 q1 = __half22float2(*reinterpret_cast<__half2*>(&raw0.y));
            float2 q2 = __half22float2(*reinterpret_cast<__half2*>(&raw0.z));
            float2 q3 = __half22float2(*reinterpret_cast<__half2*>(&raw0.w));
            acc[0] += q0.x; acc[1] += q0.y; acc[2] += q1.x; acc[3] += q1.y;
            acc[4] += q2.x; acc[5] += q2.y; acc[6] += q3.x; acc[7] += q3.y;
        }
        if (p1) {
            float2 q0 = __half22float2(*reinterpret_cast<__half2*>(&raw1.x));
            float2 q1 = __half22float2(*reinterpret_cast<__half2*>(&raw1.y));
            float2 q2 = __half22float2(*reinterpret_cast<__half2*>(&raw1.z));
            float2 q3 = __half22float2(*reinterpret_cast<__half2*>(&raw1.w));
            acc[0] += q0.x; acc[1] += q0.y; acc[2] += q1.x; acc[3] += q1.y;
            acc[4] += q2.x; acc[5] += q2.y; acc[6] += q3.x; acc[7] += q3.y;
        }
    }
#pragma unroll
    for (int o = 8; o < 64; o <<= 1) {
#pragma unroll
        for (int i = 0; i < 8; ++i) acc[i] += __shfl_xor(acc[i], o, 64);
    }
    if (lane < 8) {
        float4 raw = *reinterpret_cast<const float4*>(g1 + (size_t)wid * HID + f8);
        float2 q0 = __half22float2(*reinterpret_cast<__half2*>(&raw.x));
        float2 q1 = __half22float2(*reinterpret_cast<__half2*>(&raw.y));
        float2 q2 = __half22float2(*reinterpret_cast<__half2*>(&raw.z));
        float2 q3 = __half22float2(*reinterpret_cast<__half2*>(&raw.w));
        float dv = dinv[wid];
        float4 r0, r1;
        r0.x = dv * (acc[0] + q0.x); r0.y = dv * (acc[1] + q0.y);
        r0.z = dv * (acc[2] + q1.x); r0.w = dv * (acc[3] + q1.y);
        r1.x = dv * (acc[4] + q2.x); r1.y = dv * (acc[5] + q2.y);
        r1.z = dv * (acc[6] + q3.x); r1.w = dv * (acc[7] + q3.y);
        float4* dst4 = reinterpret_cast<float4*>(aggH + (size_t)wid * HID + f8);
        dst4[0] = r0;
        dst4[1] = r1;
    }
}

// Fused tail: H2 = relu(aggH @ W2 + b2); out = softmax(H2 @ Wout + bout).
__global__ __launch_bounds__(256) void k_fuse(const float* __restrict__ aggH,
                                              const float* __restrict__ W2,
                                              const float* __restrict__ b2,
                                              const float* __restrict__ Wout,
                                              const float* __restrict__ bout,
                                              float* __restrict__ out, int N) {
    __shared__ float4 sh4[64][17];      // aggH tile, padded (bank-spread)
    __shared__ float4 sW4[64 * 16];     // W2 row-major float4 quads
    __shared__ float  swout[64][NC];
    __shared__ float  sb2[64];
    __shared__ float  sbout[8];
    int tx = threadIdx.x;
    int nb0 = blockIdx.x * 64;

    const float4* W2_4 = reinterpret_cast<const float4*>(W2);
    for (int i = tx; i < 64 * 16; i += 256) sW4[i] = W2_4[i];
    const float4* aggH4 = reinterpret_cast<const float4*>(aggH);
    for (int i = tx; i < 64 * 16; i += 256) {
        int row = i >> 4, c4 = i & 15;
        int node = nb0 + row;
        float4 v = {0.f, 0.f, 0.f, 0.f};
        if (node < N) v = aggH4[(size_t)node * 16 + c4];
        sh4[row][c4] = v;
    }
    if (tx < 64) sb2[tx] = b2[tx];
    for (int i = tx; i < 64 * NC; i += 256) swout[i / NC][i % NC] = Wout[i];
    if (tx < NC) sbout[tx] = bout[tx];
    __syncthreads();

    int ty = tx >> 4;       // local node group: rows ty*4 .. ty*4+3
    int txl = tx & 15;      // feature quad: f = txl*4 .. txl*4+3

    float acc[4][4];
#pragma unroll
    for (int j = 0; j < 4; ++j)
#pragma unroll
        for (int i = 0; i < 4; ++i) acc[j][i] = 0.f;

    for (int k4 = 0; k4 < 16; ++k4) {
        float4 w0 = sW4[(k4 * 4 + 0) * 16 + txl];
        float4 w1 = sW4[(k4 * 4 + 1) * 16 + txl];
        float4 w2 = sW4[(k4 * 4 + 2) * 16 + txl];
        float4 w3 = sW4[(k4 * 4 + 3) * 16 + txl];
#pragma unroll
        for (int j = 0; j < 4; ++j) {
            float4 hq = sh4[ty * 4 + j][k4];
            acc[j][0] = fmaf(hq.x, w0.x, fmaf(hq.y, w1.x, fmaf(hq.z, w2.x, fmaf(hq.w, w3.x, acc[j][0]))));
            acc[j][1] = fmaf(hq.x, w0.y, fmaf(hq.y, w1.y, fmaf(hq.z, w2.y, fmaf(hq.w, w3.y, acc[j][1]))));
            acc[j][2] = fmaf(hq.x, w0.z, fmaf(hq.y, w1.z, fmaf(hq.z, w2.z, fmaf(hq.w, w3.z, acc[j][2]))));
            acc[j][3] = fmaf(hq.x, w0.w, fmaf(hq.y, w1.w, fmaf(hq.z, w2.w, fmaf(hq.w, w3.w, acc[j][3]))));
        }
    }

    float pl[4][NC];
#pragma unroll
    for (int j = 0; j < 4; ++j)
#pragma unroll
        for (int c = 0; c < NC; ++c) pl[j][c] = 0.f;
#pragma unroll
    for (int j = 0; j < 4; ++j) {
#pragma unroll
        for (int i = 0; i < 4; ++i) {
            int f = txl * 4 + i;
            float h2 = fmaxf(acc[j][i] + sb2[f], 0.f);
#pragma unroll
            for (int c = 0; c < NC; ++c) pl[j][c] = fmaf(h2, swout[f][c], pl[j][c]);
        }
    }
#pragma unroll
    for (int o = 1; o < 16; o <<= 1) {
#pragma unroll
        for (int j = 0; j < 4; ++j)
#pragma unroll
            for (int c = 0; c < NC; ++c) pl[j][c] += __shfl_xor(pl[j][c], o, 64);
    }
    if (txl == 0) {
#pragma unroll
        for (int j = 0; j < 4; ++j) {
            int node = nb0 + ty * 4 + j;
            if (node < N) {
                float lg[NC];
#pragma unroll
                for (int c = 0; c < NC; ++c) lg[c] = pl[j][c] + sbout[c];
                float m = lg[0];
#pragma unroll
                for (int c = 1; c < NC; ++c) m = fmaxf(m, lg[c]);
                float ssum = 0.f, ex[NC];
#pragma unroll
                for (int c = 0; c < NC; ++c) { ex[c] = __expf(lg[c] - m); ssum += ex[c]; }
                float inv = 1.0f / ssum;
#pragma unroll
                for (int c = 0; c < NC; ++c) out[(size_t)node * NC + c] = ex[c] * inv;
            }
        }
    }
}

// ---------------- launch ----------------

extern "C" void kernel_launch(void* const* d_in, const int* in_sizes, int n_in,
                              void* d_out, int out_size, void* d_ws, size_t ws_size,
                              hipStream_t stream) {
    const float* x   = (const float*)d_in[0];
    const int*   ei  = (const int*)d_in[1];     // [2, E]: src = ei, dst = ei+E
    const float* W1  = (const float*)d_in[3];
    const float* b1  = (const float*)d_in[4];
    const float* W2  = (const float*)d_in[5];
    const float* b2  = (const float*)d_in[6];
    const float* Wo  = (const float*)d_in[7];
    const float* bo  = (const float*)d_in[8];
    float* out = (float*)d_out;

    const int N = in_sizes[2];          // batch array length = N_NODES (assumed <= 131072)
    const int E = in_sizes[1] / 2;

    // workspace partition (256B aligned)
    size_t off = 0;
    char* base = (char*)d_ws;
    auto alloc = [&](size_t bytes) -> void* {
        off = (off + 255) & ~(size_t)255;
        void* r = base + off;
        off += bytes;
        return r;
    };
    int*      cntmat  = (int*)alloc((size_t)NBLK * NBMAX * 4);
    int*      btot    = (int*)alloc((size_t)NBMAX * 4);
    int*      bbase   = (int*)alloc(((size_t)NBMAX + 1) * 4);
    unsigned* pairbuf = (unsigned*)alloc((size_t)E * 4);
    int*      offsets = (int*)alloc(((size_t)N + 1) * 4);
    int*      csr_src = (int*)alloc((size_t)E * 4);
    float*    dinv    = (float*)alloc((size_t)N * 4);
    float*    xs8     = (float*)alloc((size_t)N * 8 * 4);
    __half*   g1      = (__half*)alloc((size_t)N * HID * 2);
    float*    aggH    = (float*)alloc((size_t)N * HID * 4);

    const int T = 256;
    int gNF = ((N * HID) + T - 1) / T;    // one wave per node (4 waves/block)

    const int* src = ei;
    const int* dst = ei + E;

    int nb = (N + WINN - 1) >> WSH;                // number of windows/buckets (<= 256)
    int chunk = (E + NBLK - 1) / NBLK;             // edges per fill block

    // bucketed CSR build (+ xs8 table)
    k_bcount<<<NBLK, 512, 0, stream>>>(dst, E, chunk, nb, cntmat);
    k_wscan<<<nb, NBLK, 0, stream>>>(cntmat, nb, btot);
    k_bscan2<<<1, 256, 0, stream>>>(btot, nb, N, bbase, offsets);
    k_bfill<<<NBLK, 512, 0, stream>>>(src, dst, E, chunk, nb, bbase, cntmat, pairbuf);
    k_csr<<<nb, WINN, 0, stream>>>(pairbuf, bbase, N, x, offsets, csr_src, dinv, xs8);

    // layer 1: aggregate xs8 in input space, then @W1 per node: g1 = relu(.)*dinv (fp16)
    k_aggX<<<gNF, T, 0, stream>>>(xs8, W1, offsets, csr_src, dinv, b1, g1, N);

    // layer 2 aggregation BEFORE matmul: aggH = dinv*(g1 + Σ g1[s])
    k_aggG<<<gNF, T, 0, stream>>>(g1, offsets, csr_src, dinv, aggH, N);

    // fused tail: relu(aggH@W2+b2) @ Wout + bout -> softmax -> out
    int nbF = (N + 63) / 64;
    k_fuse<<<nbF, 256, 0, stream>>>(aggH, W2, b2, Wo, bo, out, N);
}

// Round 11
// 201.699 us; speedup vs baseline: 4.8269x; 1.0385x over previous
//
#include <hip/hip_runtime.h>
#include <hip/hip_fp16.h>

#define HID 64
#define NF 5
#define NC 5

#define WSH 9                 // window shift: 512 nodes per window
#define WINN 512              // nodes per window (== blockDim of k_csr)
#define NBMAX 256             // max windows (N <= 131072)
#define SRCB 17               // bits for src in packed pair (N <= 131072); dstLocal 9 bits
#define NBLK 256              // blocks for bcount/bfill

// ---------------- bucketed CSR build ----------------

// Pass 1: per-(block,bucket) histogram -> cntmat[blk][bucket] (coalesced store).
// int4-vectorized dst reads (chunk is a multiple of 4; dst base 16B-aligned).
__global__ __launch_bounds__(512) void k_bcount(const int* __restrict__ dst, int E, int chunk,
                                                int nb, int* __restrict__ cntmat) {
    __shared__ int cnt[NBMAX];
    int t = threadIdx.x;
    for (int i = t; i < nb; i += 512) cnt[i] = 0;
    __syncthreads();
    int c0 = blockIdx.x * chunk;
    int c1 = c0 + chunk; if (c1 > E) c1 = E;
    for (int i = c0 + t * 4; i < c1; i += 512 * 4) {
        if (i + 3 < c1) {
            int4 d4 = *reinterpret_cast<const int4*>(dst + i);
            atomicAdd(&cnt[d4.x >> WSH], 1);
            atomicAdd(&cnt[d4.y >> WSH], 1);
            atomicAdd(&cnt[d4.z >> WSH], 1);
            atomicAdd(&cnt[d4.w >> WSH], 1);
        } else {
            for (int k = i; k < c1; ++k) atomicAdd(&cnt[dst[k] >> WSH], 1);
        }
    }
    __syncthreads();
    for (int i = t; i < nb; i += 512) cntmat[blockIdx.x * nb + i] = cnt[i];
}

// Pass 2a: per-bucket exclusive scan over the NBLK block counts (in place) + btot.
__global__ __launch_bounds__(NBLK) void k_wscan(int* __restrict__ cntmat, int nb,
                                                int* __restrict__ btot) {
    __shared__ int s[NBLK];
    int b = blockIdx.x;       // bucket
    int t = threadIdx.x;      // block index
    int v = cntmat[t * nb + b];
    s[t] = v;
    __syncthreads();
    for (int o = 1; o < NBLK; o <<= 1) {
        int u = (t >= o) ? s[t - o] : 0;
        __syncthreads();
        s[t] += u;
        __syncthreads();
    }
    cntmat[t * nb + b] = s[t] - v;            // exclusive prefix within bucket
    if (t == NBLK - 1) btot[b] = s[t];
}

// Pass 2b: exclusive scan of bucket totals -> bbase; offsets[N] = E.
__global__ __launch_bounds__(256) void k_bscan2(const int* __restrict__ btot, int nb, int N,
                                                int* __restrict__ bbase,
                                                int* __restrict__ offsets) {
    __shared__ int s[256];
    int t = threadIdx.x;
    int v = (t < nb) ? btot[t] : 0;
    s[t] = v;
    __syncthreads();
    for (int o = 1; o < 256; o <<= 1) {
        int u = (t >= o) ? s[t - o] : 0;
        __syncthreads();
        s[t] += u;
        __syncthreads();
    }
    if (t < nb) bbase[t] = s[t] - v;
    if (t == nb - 1) { bbase[nb] = s[t]; offsets[N] = s[t]; }
}

// Pass 3: scatter-only fill (bases precomputed); int4-vectorized src/dst reads.
__global__ __launch_bounds__(512) void k_bfill(const int* __restrict__ src,
                                               const int* __restrict__ dst, int E, int chunk,
                                               int nb, const int* __restrict__ bbase,
                                               const int* __restrict__ cntmat,
                                               unsigned int* __restrict__ pairbuf) {
    __shared__ int wcur[NBMAX];
    int t = threadIdx.x;
    int blk = blockIdx.x;
    for (int i = t; i < nb; i += 512)
        wcur[i] = bbase[i] + cntmat[blk * nb + i];
    __syncthreads();
    int c0 = blk * chunk;
    int c1 = c0 + chunk; if (c1 > E) c1 = E;
    for (int i = c0 + t * 4; i < c1; i += 512 * 4) {
        if (i + 3 < c1) {
            int4 d4 = *reinterpret_cast<const int4*>(dst + i);
            int4 s4 = *reinterpret_cast<const int4*>(src + i);
            int p;
            p = atomicAdd(&wcur[d4.x >> WSH], 1);
            pairbuf[p] = ((unsigned)(d4.x & (WINN - 1)) << SRCB) | (unsigned)s4.x;
            p = atomicAdd(&wcur[d4.y >> WSH], 1);
            pairbuf[p] = ((unsigned)(d4.y & (WINN - 1)) << SRCB) | (unsigned)s4.y;
            p = atomicAdd(&wcur[d4.z >> WSH], 1);
            pairbuf[p] = ((unsigned)(d4.z & (WINN - 1)) << SRCB) | (unsigned)s4.z;
            p = atomicAdd(&wcur[d4.w >> WSH], 1);
            pairbuf[p] = ((unsigned)(d4.w & (WINN - 1)) << SRCB) | (unsigned)s4.w;
        } else {
            for (int k = i; k < c1; ++k) {
                int d = dst[k];
                int p = atomicAdd(&wcur[d >> WSH], 1);
                pairbuf[p] = ((unsigned)(d & (WINN - 1)) << SRCB) | (unsigned)src[k];
            }
        }
    }
}

// Pass 4: one block per 512-node window. Exclusive ownership of pair/CSR region.
// Emits offsets, csr_src, dinv, and xs8[n] = {x[n,3,:]*dinv[n], pad 0} (32 B rows).
__global__ __launch_bounds__(WINN) void k_csr(const unsigned int* __restrict__ pairbuf,
                                              const int* __restrict__ bbase, int N,
                                              const float* __restrict__ x,
                                              int* __restrict__ offsets,
                                              int* __restrict__ csr_src,
                                              float* __restrict__ dinv,
                                              float* __restrict__ xs8) {
    int b = blockIdx.x, t = threadIdx.x;
    int winStart = b << WSH;
    int rbeg = bbase[b], rend = bbase[b + 1];
    __shared__ int deg[WINN];
    __shared__ int cur[WINN];
    __shared__ int s[WINN];
    deg[t] = 0;
    __syncthreads();
    for (int p = rbeg + t; p < rend; p += WINN)
        atomicAdd(&deg[pairbuf[p] >> SRCB], 1);
    __syncthreads();
    int v = deg[t];
    s[t] = v;
    __syncthreads();
    for (int o = 1; o < WINN; o <<= 1) {
        int u = (t >= o) ? s[t - o] : 0;
        __syncthreads();
        s[t] += u;
        __syncthreads();
    }
    int node = winStart + t;
    if (node < N) {
        int base = rbeg + s[t] - v;
        offsets[node] = base;
        cur[t] = base;
        float dv = rsqrtf((float)v + 1.0f);
        dinv[node] = dv;
        const float* xr = x + (size_t)node * (4 * NF) + 3 * NF;
        float4 v0, v1;
        v0.x = xr[0] * dv; v0.y = xr[1] * dv; v0.z = xr[2] * dv; v0.w = xr[3] * dv;
        v1.x = xr[4] * dv; v1.y = 0.f; v1.z = 0.f; v1.w = 0.f;
        float4* xp = reinterpret_cast<float4*>(xs8 + (size_t)node * 8);
        xp[0] = v0;
        xp[1] = v1;
    }
    __syncthreads();
    for (int p = rbeg + t; p < rend; p += WINN) {
        unsigned u = pairbuf[p];
        int dl = u >> SRCB;
        int sn = u & ((1u << SRCB) - 1);
        int pos = atomicAdd(&cur[dl], 1);
        csr_src[pos] = sn;
    }
}

// ---------------- GCN layers ----------------

// Layer-1, aggregation in padded 8-float input space; g1 stored as fp16.
// g1[d] = relu( dinv[d]*(xs[d] + Σ_s xs[s]) @ W1 + b1 ) * dinv[d]
// Wave: 32 edge groups (g=lane>>1) x 2 lanes; lane h=lane&1 loads float4 half-row.
__global__ __launch_bounds__(256) void k_aggX(const float* __restrict__ xs8,
                                              const float* __restrict__ W1,
                                              const int* __restrict__ offsets,
                                              const int* __restrict__ csr_src,
                                              const float* __restrict__ dinv,
                                              const float* __restrict__ b1,
                                              __half* __restrict__ g1, int N) {
    int wid = (blockIdx.x * blockDim.x + threadIdx.x) >> 6;
    int lane = threadIdx.x & 63;
    int g = lane >> 1;              // 32 edge groups
    int h = lane & 1;               // half-row selector (features h*4..h*4+3)
    // W1 column for this lane's output feature (5 regs, coalesced across lanes)
    float w0 = W1[0 * HID + lane], w1 = W1[1 * HID + lane], w2 = W1[2 * HID + lane],
          w3 = W1[3 * HID + lane], w4 = W1[4 * HID + lane];
    if (wid >= N) return;
    int e0 = offsets[wid], e1 = offsets[wid + 1];
    float4 acc = {0.f, 0.f, 0.f, 0.f};
    int ee = e0 + g;
    int s = (ee < e1) ? csr_src[ee] : -1;
    for (int e = e0; e < e1; e += 32) {
        int cs = s;
        int en = e + 32 + g;
        s = (en < e1) ? csr_src[en] : -1;       // prefetch next iter's index
        bool p = (cs >= 0);
        int csc = p ? cs : 0;                   // clamp: load always (exec-unmasked)
        float4 v = *reinterpret_cast<const float4*>(xs8 + (size_t)csc * 8 + (h << 2));
        if (p) { acc.x += v.x; acc.y += v.y; acc.z += v.z; acc.w += v.w; }
    }
    if (g == 0) {                               // self term (lanes 0,1)
        float4 v = *reinterpret_cast<const float4*>(xs8 + (size_t)wid * 8 + (h << 2));
        acc.x += v.x; acc.y += v.y; acc.z += v.z; acc.w += v.w;
    }
    // reduce across the 32 edge groups (partners share h)
#pragma unroll
    for (int o = 2; o < 64; o <<= 1) {
        acc.x += __shfl_xor(acc.x, o, 64);
        acc.y += __shfl_xor(acc.y, o, 64);
        acc.z += __shfl_xor(acc.z, o, 64);
        acc.w += __shfl_xor(acc.w, o, 64);
    }
    // gather the 5 aggregated features from the two h-classes
    float a0 = __shfl(acc.x, 0, 2), a1 = __shfl(acc.y, 0, 2),
          a2 = __shfl(acc.z, 0, 2), a3 = __shfl(acc.w, 0, 2),
          a4 = __shfl(acc.x, 1, 2);
    float dv = dinv[wid];
    float sres = a0 * w0 + a1 * w1 + a2 * w2 + a3 * w3 + a4 * w4;
    float r = fmaxf(fmaf(dv, sres, b1[lane]), 0.f) * dv;  // g1 = relu(.)*dinv
    g1[(size_t)wid * HID + lane] = __float2half(r);
}

// Layer-2 pre-matmul aggregate over fp16 g1 rows (128 B each), unroll x4:
// 32 rows in flight per wave. aggH[d] = dinv[d]*( g1[d] + Σ_s g1[s] ), fp16 out.
__global__ __launch_bounds__(256) void k_aggG(const __half* __restrict__ g1,
                                              const int* __restrict__ offsets,
                                              const int* __restrict__ csr_src,
                                              const float* __restrict__ dinv,
                                              __half* __restrict__ aggH, int N) {
    int wid = (blockIdx.x * blockDim.x + threadIdx.x) >> 6;
    if (wid >= N) return;
    int lane = threadIdx.x & 63;
    int g = lane >> 3;              // 8 edge groups
    int f8 = (lane & 7) << 3;       // 8 features per lane
    int e0 = offsets[wid], e1 = offsets[wid + 1];
    float acc[8];
#pragma unroll
    for (int i = 0; i < 8; ++i) acc[i] = 0.f;
    int ee = e0 + g;
    int s0 = (ee < e1) ? csr_src[ee] : -1;
    int s1 = (ee + 8 < e1) ? csr_src[ee + 8] : -1;
    int s2 = (ee + 16 < e1) ? csr_src[ee + 16] : -1;
    int s3 = (ee + 24 < e1) ? csr_src[ee + 24] : -1;
    for (int e = e0; e < e1; e += 32) {
        int cs0 = s0, cs1 = s1, cs2 = s2, cs3 = s3;
        int nb0 = e + 32 + g;
        s0 = (nb0 < e1) ? csr_src[nb0] : -1;    // prefetch next iter's indices
        s1 = (nb0 + 8 < e1) ? csr_src[nb0 + 8] : -1;
        s2 = (nb0 + 16 < e1) ? csr_src[nb0 + 16] : -1;
        s3 = (nb0 + 24 < e1) ? csr_src[nb0 + 24] : -1;
        bool p0 = (cs0 >= 0), p1 = (cs1 >= 0), p2 = (cs2 >= 0), p3 = (cs3 >= 0);
        int c0 = p0 ? cs0 : 0, c1 = p1 ? cs1 : 0, c2 = p2 ? cs2 : 0, c3 = p3 ? cs3 : 0;
        float4 raw0 = *reinterpret_cast<const float4*>(g1 + (size_t)c0 * HID + f8);
        float4 raw1 = *reinterpret_cast<const float4*>(g1 + (size_t)c1 * HID + f8);
        float4 raw2 = *reinterpret_cast<const float4*>(g1 + (size_t)c2 * HID + f8);
        float4 raw3 = *reinterpret_cast<const float4*>(g1 + (size_t)c3 * HID + f8);
        if (p0) {
            float2 q0 = __half22float2(*reinterpret_cast<__half2*>(&raw0.x));
            float2 q1 = __half22float2(*reinterpret_cast<__half2*>(&raw0.y));
            float2 q2 = __half22float2(*reinterpret_cast<__half2*>(&raw0.z));
            float2 q3 = __half22float2(*reinterpret_cast<__half2*>(&raw0.w));
            acc[0] += q0.x; acc[1] += q0.y; acc[2] += q1.x; acc[3] += q1.y;
            acc[4] += q2.x; acc[5] += q2.y; acc[6] += q3.x; acc[7] += q3.y;
        }
        if (p1) {
            float2 q0 = __half22float2(*reinterpret_cast<__half2*>(&raw1.x));
            float2 q1 = __half22float2(*reinterpret_cast<__half2*>(&raw1.y));
            float2 q2 = __half22float2(*reinterpret_cast<__half2*>(&raw1.z));
            float2 q3 = __half22float2(*reinterpret_cast<__half2*>(&raw1.w));
            acc[0] += q0.x; acc[1] += q0.y; acc[2] += q1.x; acc[3] += q1.y;
            acc[4] += q2.x; acc[5] += q2.y; acc[6] += q3.x; acc[7] += q3.y;
        }
        if (p2) {
            float2 q0 = __half22float2(*reinterpret_cast<__half2*>(&raw2.x));
            float2 q1 = __half22float2(*reinterpret_cast<__half2*>(&raw2.y));
            float2 q2 = __half22float2(*reinterpret_cast<__half2*>(&raw2.z));
            float2 q3 = __half22float2(*reinterpret_cast<__half2*>(&raw2.w));
            acc[0] += q0.x; acc[1] += q0.y; acc[2] += q1.x; acc[3] += q1.y;
            acc[4] += q2.x; acc[5] += q2.y; acc[6] += q3.x; acc[7] += q3.y;
        }
        if (p3) {
            float2 q0 = __half22float2(*reinterpret_cast<__half2*>(&raw3.x));
            float2 q1 = __half22float2(*reinterpret_cast<__half2*>(&raw3.y));
            float2 q2 = __half22float2(*reinterpret_cast<__half2*>(&raw3.z));
            float2 q3 = __half22float2(*reinterpret_cast<__half2*>(&raw3.w));
            acc[0] += q0.x; acc[1] += q0.y; acc[2] += q1.x; acc[3] += q1.y;
            acc[4] += q2.x; acc[5] += q2.y; acc[6] += q3.x; acc[7] += q3.y;
        }
    }
#pragma unroll
    for (int o = 8; o < 64; o <<= 1) {
#pragma unroll
        for (int i = 0; i < 8; ++i) acc[i] += __shfl_xor(acc[i], o, 64);
    }
    if (lane < 8) {
        float4 raw = *reinterpret_cast<const float4*>(g1 + (size_t)wid * HID + f8);
        float2 q0 = __half22float2(*reinterpret_cast<__half2*>(&raw.x));
        float2 q1 = __half22float2(*reinterpret_cast<__half2*>(&raw.y));
        float2 q2 = __half22float2(*reinterpret_cast<__half2*>(&raw.z));
        float2 q3 = __half22float2(*reinterpret_cast<__half2*>(&raw.w));
        float dv = dinv[wid];
        float4 st;
        *reinterpret_cast<__half2*>(&st.x) = __floats2half2_rn(dv * (acc[0] + q0.x), dv * (acc[1] + q0.y));
        *reinterpret_cast<__half2*>(&st.y) = __floats2half2_rn(dv * (acc[2] + q1.x), dv * (acc[3] + q1.y));
        *reinterpret_cast<__half2*>(&st.z) = __floats2half2_rn(dv * (acc[4] + q2.x), dv * (acc[5] + q2.y));
        *reinterpret_cast<__half2*>(&st.w) = __floats2half2_rn(dv * (acc[6] + q3.x), dv * (acc[7] + q3.y));
        *reinterpret_cast<float4*>(aggH + (size_t)wid * HID + f8) = st;
    }
}

// Fused tail: H2 = relu(aggH @ W2 + b2); out = softmax(H2 @ Wout + bout).
// aggH is fp16 (128 B rows); converted to fp32 during the LDS stage.
__global__ __launch_bounds__(256) void k_fuse(const __half* __restrict__ aggH,
                                              const float* __restrict__ W2,
                                              const float* __restrict__ b2,
                                              const float* __restrict__ Wout,
                                              const float* __restrict__ bout,
                                              float* __restrict__ out, int N) {
    __shared__ float4 sh4[64][17];      // aggH tile, padded (bank-spread)
    __shared__ float4 sW4[64 * 16];     // W2 row-major float4 quads
    __shared__ float  swout[64][NC];
    __shared__ float  sb2[64];
    __shared__ float  sbout[8];
    int tx = threadIdx.x;
    int nb0 = blockIdx.x * 64;

    const float4* W2_4 = reinterpret_cast<const float4*>(W2);
    for (int i = tx; i < 64 * 16; i += 256) sW4[i] = W2_4[i];
    const float4* aggH4 = reinterpret_cast<const float4*>(aggH);  // 8 halves per float4
    for (int i = tx; i < 64 * 8; i += 256) {
        int row = i >> 3, h8 = i & 7;
        int node = nb0 + row;
        float4 raw = {0.f, 0.f, 0.f, 0.f};
        if (node < N) raw = aggH4[(size_t)node * 8 + h8];
        float2 q0 = __half22float2(*reinterpret_cast<__half2*>(&raw.x));
        float2 q1 = __half22float2(*reinterpret_cast<__half2*>(&raw.y));
        float2 q2 = __half22float2(*reinterpret_cast<__half2*>(&raw.z));
        float2 q3 = __half22float2(*reinterpret_cast<__half2*>(&raw.w));
        sh4[row][h8 * 2]     = make_float4(q0.x, q0.y, q1.x, q1.y);
        sh4[row][h8 * 2 + 1] = make_float4(q2.x, q2.y, q3.x, q3.y);
    }
    if (tx < 64) sb2[tx] = b2[tx];
    for (int i = tx; i < 64 * NC; i += 256) swout[i / NC][i % NC] = Wout[i];
    if (tx < NC) sbout[tx] = bout[tx];
    __syncthreads();

    int ty = tx >> 4;       // local node group: rows ty*4 .. ty*4+3
    int txl = tx & 15;      // feature quad: f = txl*4 .. txl*4+3

    float acc[4][4];
#pragma unroll
    for (int j = 0; j < 4; ++j)
#pragma unroll
        for (int i = 0; i < 4; ++i) acc[j][i] = 0.f;

    for (int k4 = 0; k4 < 16; ++k4) {
        float4 w0 = sW4[(k4 * 4 + 0) * 16 + txl];
        float4 w1 = sW4[(k4 * 4 + 1) * 16 + txl];
        float4 w2 = sW4[(k4 * 4 + 2) * 16 + txl];
        float4 w3 = sW4[(k4 * 4 + 3) * 16 + txl];
#pragma unroll
        for (int j = 0; j < 4; ++j) {
            float4 hq = sh4[ty * 4 + j][k4];
            acc[j][0] = fmaf(hq.x, w0.x, fmaf(hq.y, w1.x, fmaf(hq.z, w2.x, fmaf(hq.w, w3.x, acc[j][0]))));
            acc[j][1] = fmaf(hq.x, w0.y, fmaf(hq.y, w1.y, fmaf(hq.z, w2.y, fmaf(hq.w, w3.y, acc[j][1]))));
            acc[j][2] = fmaf(hq.x, w0.z, fmaf(hq.y, w1.z, fmaf(hq.z, w2.z, fmaf(hq.w, w3.z, acc[j][2]))));
            acc[j][3] = fmaf(hq.x, w0.w, fmaf(hq.y, w1.w, fmaf(hq.z, w2.w, fmaf(hq.w, w3.w, acc[j][3]))));
        }
    }

    float pl[4][NC];
#pragma unroll
    for (int j = 0; j < 4; ++j)
#pragma unroll
        for (int c = 0; c < NC; ++c) pl[j][c] = 0.f;
#pragma unroll
    for (int j = 0; j < 4; ++j) {
#pragma unroll
        for (int i = 0; i < 4; ++i) {
            int f = txl * 4 + i;
            float h2 = fmaxf(acc[j][i] + sb2[f], 0.f);
#pragma unroll
            for (int c = 0; c < NC; ++c) pl[j][c] = fmaf(h2, swout[f][c], pl[j][c]);
        }
    }
#pragma unroll
    for (int o = 1; o < 16; o <<= 1) {
#pragma unroll
        for (int j = 0; j < 4; ++j)
#pragma unroll
            for (int c = 0; c < NC; ++c) pl[j][c] += __shfl_xor(pl[j][c], o, 64);
    }
    if (txl == 0) {
#pragma unroll
        for (int j = 0; j < 4; ++j) {
            int node = nb0 + ty * 4 + j;
            if (node < N) {
                float lg[NC];
#pragma unroll
                for (int c = 0; c < NC; ++c) lg[c] = pl[j][c] + sbout[c];
                float m = lg[0];
#pragma unroll
                for (int c = 1; c < NC; ++c) m = fmaxf(m, lg[c]);
                float ssum = 0.f, ex[NC];
#pragma unroll
                for (int c = 0; c < NC; ++c) { ex[c] = __expf(lg[c] - m); ssum += ex[c]; }
                float inv = 1.0f / ssum;
#pragma unroll
                for (int c = 0; c < NC; ++c) out[(size_t)node * NC + c] = ex[c] * inv;
            }
        }
    }
}

// ---------------- launch ----------------

extern "C" void kernel_launch(void* const* d_in, const int* in_sizes, int n_in,
                              void* d_out, int out_size, void* d_ws, size_t ws_size,
                              hipStream_t stream) {
    const float* x   = (const float*)d_in[0];
    const int*   ei  = (const int*)d_in[1];     // [2, E]: src = ei, dst = ei+E
    const float* W1  = (const float*)d_in[3];
    const float* b1  = (const float*)d_in[4];
    const float* W2  = (const float*)d_in[5];
    const float* b2  = (const float*)d_in[6];
    const float* Wo  = (const float*)d_in[7];
    const float* bo  = (const float*)d_in[8];
    float* out = (float*)d_out;

    const int N = in_sizes[2];          // batch array length = N_NODES (assumed <= 131072)
    const int E = in_sizes[1] / 2;

    // workspace partition (256B aligned)
    size_t off = 0;
    char* base = (char*)d_ws;
    auto alloc = [&](size_t bytes) -> void* {
        off = (off + 255) & ~(size_t)255;
        void* r = base + off;
        off += bytes;
        return r;
    };
    int*      cntmat  = (int*)alloc((size_t)NBLK * NBMAX * 4);
    int*      btot    = (int*)alloc((size_t)NBMAX * 4);
    int*      bbase   = (int*)alloc(((size_t)NBMAX + 1) * 4);
    unsigned* pairbuf = (unsigned*)alloc((size_t)E * 4);
    int*      offsets = (int*)alloc(((size_t)N + 1) * 4);
    int*      csr_src = (int*)alloc((size_t)E * 4);
    float*    dinv    = (float*)alloc((size_t)N * 4);
    float*    xs8     = (float*)alloc((size_t)N * 8 * 4);
    __half*   g1      = (__half*)alloc((size_t)N * HID * 2);
    __half*   aggH    = (__half*)alloc((size_t)N * HID * 2);

    const int T = 256;
    int gNF = ((N * HID) + T - 1) / T;    // one wave per node (4 waves/block)

    const int* src = ei;
    const int* dst = ei + E;

    int nb = (N + WINN - 1) >> WSH;                      // number of windows/buckets (<= 256)
    int chunk = (((E + NBLK - 1) / NBLK) + 3) & ~3;      // edges per fill block, multiple of 4

    // bucketed CSR build (+ xs8 table)
    k_bcount<<<NBLK, 512, 0, stream>>>(dst, E, chunk, nb, cntmat);
    k_wscan<<<nb, NBLK, 0, stream>>>(cntmat, nb, btot);
    k_bscan2<<<1, 256, 0, stream>>>(btot, nb, N, bbase, offsets);
    k_bfill<<<NBLK, 512, 0, stream>>>(src, dst, E, chunk, nb, bbase, cntmat, pairbuf);
    k_csr<<<nb, WINN, 0, stream>>>(pairbuf, bbase, N, x, offsets, csr_src, dinv, xs8);

    // layer 1: aggregate xs8 in input space, then @W1 per node: g1 = relu(.)*dinv (fp16)
    k_aggX<<<gNF, T, 0, stream>>>(xs8, W1, offsets, csr_src, dinv, b1, g1, N);

    // layer 2 aggregation BEFORE matmul: aggH = dinv*(g1 + Σ g1[s]) (fp16)
    k_aggG<<<gNF, T, 0, stream>>>(g1, offsets, csr_src, dinv, aggH, N);

    // fused tail: relu(aggH@W2+b2) @ Wout + bout -> softmax -> out
    int nbF = (N + 63) / 64;
    k_fuse<<<nbF, 256, 0, stream>>>(aggH, W2, b2, Wo, bo, out, N);
}